// Round 6
// baseline (252.414 us; speedup 1.0000x reference)
//
#include <hip/hip_runtime.h>
#include <hip/hip_bf16.h>
#include <math.h>

#define BB 8
#define C1D 384
#define C2D 192
#define LDIM 4096
#define ADIM 384
#define NH 8
#define DHD 48
#define KVLC 16
#define KVP_STRIDE 2352   // 48*48 partials + 48 expsums
#define LN_EPS 1e-5f

typedef short s8v __attribute__((ext_vector_type(8)));
typedef float f4v __attribute__((ext_vector_type(4)));

__device__ __forceinline__ unsigned short f2bf(float f) {
    unsigned u = __builtin_bit_cast(unsigned, f);
    unsigned r = (u + 0x7FFFu + ((u >> 16) & 1u)) >> 16;
    return (unsigned short)r;
}
__device__ __forceinline__ float bf2f(unsigned short h) {
    unsigned u = ((unsigned)h) << 16;
    return __builtin_bit_cast(float, u);
}
__device__ __forceinline__ void gload16(const void* g, void* l) {
    __builtin_amdgcn_global_load_lds((const __attribute__((address_space(1))) void*)g,
                                     (__attribute__((address_space(3))) void*)l, 16, 0, 0);
}

// ---------- transpose fp32 [bz][R][Cols] -> bf16 [bz][Cols][R] ----------
__global__ __launch_bounds__(256) void transpose_cvt(const float* __restrict__ in,
                                                     unsigned short* __restrict__ out,
                                                     int R, int Cols)
{
    __shared__ float T[32][33];
    int b = blockIdx.z;
    int c0 = blockIdx.x * 32, r0 = blockIdx.y * 32;
    const float* ib = in + (size_t)b * R * Cols;
    unsigned short* ob = out + (size_t)b * R * Cols;
    int t = threadIdx.x;
#pragma unroll
    for (int i = 0; i < 4; ++i) {
        int idx = t + i * 256;
        int rr = idx >> 5, cc = idx & 31;
        T[rr][cc] = ib[(size_t)(r0 + rr) * Cols + c0 + cc];
    }
    __syncthreads();
#pragma unroll
    for (int i = 0; i < 2; ++i) {
        int idx = t + i * 256;
        int cc = idx >> 4, rp = (idx & 15) * 2;
        unsigned val = (unsigned)f2bf(T[rp][cc]) | ((unsigned)f2bf(T[rp + 1][cc]) << 16);
        *(unsigned*)&ob[(size_t)(c0 + cc) * R + r0 + rp] = val;
    }
}

// ---------- bf16 MFMA GEMM: Out[b,m,n] = scl*(sum_k A[b,m,k]*Bt[b,n,k] + bias) ----------
// BMODE: 0 = no bias, 1 = bias over n, 2 = bias over m
template<int KD, int BMODE>
__global__ __launch_bounds__(256) void gemm_mfma(
    const unsigned short* __restrict__ A, size_t Abs,
    const unsigned short* __restrict__ Bt, size_t Bbs,
    const float* __restrict__ bias,
    unsigned short* __restrict__ Out, size_t Obs, int Ncols, float scl)
{
    __shared__ unsigned short As[128 * 64];
    __shared__ unsigned short Bs[128 * 64];
    const int t = threadIdx.x;
    const int lane = t & 63;
    const int w = t >> 6;
    const int wm = w >> 1, wn = w & 1;
    const int b = blockIdx.z;
    const int m0 = blockIdx.x * 128;
    const int n0 = blockIdx.y * 128;

    const unsigned short* Ab = A + Abs * b + (size_t)m0 * KD;
    const unsigned short* Bb = Bt + Bbs * b + (size_t)n0 * KD;

    f4v acc[4][4];
#pragma unroll
    for (int i = 0; i < 4; ++i)
#pragma unroll
        for (int j = 0; j < 4; ++j) acc[i][j] = (f4v)0.f;

    const int r_l = lane >> 3;
    const int q = lane & 7;

    for (int ks = 0; ks < KD; ks += 64) {
#pragma unroll
        for (int c = 0; c < 4; ++c) {
            int row = w * 32 + c * 8 + r_l;
            int koff = ((q ^ (row & 7)) << 3);
            gload16(Ab + (size_t)row * KD + ks + koff, &As[(w * 32 + c * 8) * 64]);
            gload16(Bb + (size_t)row * KD + ks + koff, &Bs[(w * 32 + c * 8) * 64]);
        }
        __syncthreads();
#pragma unroll
        for (int kh = 0; kh < 2; ++kh) {
            s8v af[4], bfr[4];
            int kq = kh * 4 + (lane >> 4);
#pragma unroll
            for (int m = 0; m < 4; ++m) {
                int row = wm * 64 + m * 16 + (lane & 15);
                af[m] = *(const s8v*)&As[row * 64 + ((kq ^ (row & 7)) << 3)];
            }
#pragma unroll
            for (int n = 0; n < 4; ++n) {
                int row = wn * 64 + n * 16 + (lane & 15);
                bfr[n] = *(const s8v*)&Bs[row * 64 + ((kq ^ (row & 7)) << 3)];
            }
#pragma unroll
            for (int m = 0; m < 4; ++m)
#pragma unroll
                for (int n = 0; n < 4; ++n)
                    acc[m][n] = __builtin_amdgcn_mfma_f32_16x16x32_bf16(af[m], bfr[n], acc[m][n], 0, 0, 0);
        }
        __syncthreads();
    }

    float bn[4], bm[4][4];
    if (BMODE == 2) {
#pragma unroll
        for (int m = 0; m < 4; ++m)
#pragma unroll
            for (int r = 0; r < 4; ++r)
                bm[m][r] = bias[m0 + wm * 64 + m * 16 + (lane >> 4) * 4 + r];
    } else if (BMODE == 1) {
#pragma unroll
        for (int n = 0; n < 4; ++n) bn[n] = bias[n0 + wn * 64 + n * 16 + (lane & 15)];
    }
#pragma unroll
    for (int m = 0; m < 4; ++m)
#pragma unroll
        for (int n = 0; n < 4; ++n) {
            int col = n0 + wn * 64 + n * 16 + (lane & 15);
#pragma unroll
            for (int r = 0; r < 4; ++r) {
                int row = m0 + wm * 64 + m * 16 + (lane >> 4) * 4 + r;
                float bb = (BMODE == 2) ? bm[m][r] : (BMODE == 1) ? bn[n] : 0.f;
                float v = (acc[m][n][r] + bb) * scl;
                Out[Obs * b + (size_t)row * Ncols + col] = f2bf(v);
            }
        }
}

// ---------- kvpart[bh][lc][e*48+d] = partial sum_l Vt[e][l]*exp(Kt[d][l]); +expsums[d] ----------
__global__ __launch_bounds__(64) void kv_part(const unsigned short* __restrict__ Kt,
                                              const unsigned short* __restrict__ Vt,
                                              float* __restrict__ kvpart)
{
    int lane = threadIdx.x;
    int b = blockIdx.z, h = blockIdx.y, lc = blockIdx.x;
    size_t base = ((size_t)b * ADIM + h * DHD) * LDIM;
    const unsigned short* Kb = Kt + base;
    const unsigned short* Vb = Vt + base;
    int lbase = lc * (LDIM / KVLC);

    f4v acc[3][3];
#pragma unroll
    for (int i = 0; i < 3; ++i)
#pragma unroll
        for (int j = 0; j < 3; ++j) acc[i][j] = (f4v)0.f;
    float es[3] = {0.f, 0.f, 0.f};

    for (int ks = 0; ks < LDIM / KVLC; ks += 32) {
        int l0 = lbase + ks + ((lane >> 4) * 8);
        s8v af[3], bfr[3];
#pragma unroll
        for (int me = 0; me < 3; ++me)
            af[me] = *(const s8v*)&Vb[(size_t)(me * 16 + (lane & 15)) * LDIM + l0];
#pragma unroll
        for (int nd = 0; nd < 3; ++nd) {
            s8v raw = *(const s8v*)&Kb[(size_t)(nd * 16 + (lane & 15)) * LDIM + l0];
#pragma unroll
            for (int j = 0; j < 8; ++j) {
                float e = __expf(bf2f((unsigned short)raw[j]));
                es[nd] += e;
                bfr[nd][j] = (short)f2bf(e);
            }
        }
#pragma unroll
        for (int me = 0; me < 3; ++me)
#pragma unroll
            for (int nd = 0; nd < 3; ++nd)
                acc[me][nd] = __builtin_amdgcn_mfma_f32_16x16x32_bf16(af[me], bfr[nd], acc[me][nd], 0, 0, 0);
    }
    float* pp = kvpart + (((size_t)(b * NH + h) * KVLC) + lc) * KVP_STRIDE;
#pragma unroll
    for (int me = 0; me < 3; ++me)
#pragma unroll
        for (int nd = 0; nd < 3; ++nd)
#pragma unroll
            for (int r = 0; r < 4; ++r) {
                int e = me * 16 + (lane >> 4) * 4 + r;   // C/D row
                int d = nd * 16 + (lane & 15);           // C/D col
                pp[e * DHD + d] = acc[me][nd][r];
            }
    // reduce exp-sums across the 4 k-subgroup lanes (same d = nd*16 + (lane&15))
#pragma unroll
    for (int nd = 0; nd < 3; ++nd) {
        float s = es[nd];
        s += __shfl_xor(s, 16, 64);
        s += __shfl_xor(s, 32, 64);
        if (lane < 16) pp[2304 + nd * 16 + lane] = s;
    }
}

// ---------- KVf[bh][d*48+e] = (sum_lc part[e][d]) / (sum_lc expsum[d]) ----------
__global__ __launch_bounds__(256) void kv_finalize(const float* __restrict__ kvpart,
                                                   float* __restrict__ KVf)
{
    __shared__ float isl_s[DHD];
    int bh = blockIdx.x, t = threadIdx.x;
    const float* pp = kvpart + (size_t)bh * KVLC * KVP_STRIDE;
    if (t < DHD) {
        float s = 0.f;
#pragma unroll
        for (int lc = 0; lc < KVLC; ++lc) s += pp[lc * KVP_STRIDE + 2304 + t];
        isl_s[t] = 1.f / s;
    }
    __syncthreads();
    for (int idx = t; idx < DHD * DHD; idx += 256) {
        int d = idx / DHD, e = idx % DHD;
        float s = 0.f;
#pragma unroll
        for (int lc = 0; lc < KVLC; ++lc) s += pp[lc * KVP_STRIDE + e * DHD + d];
        KVf[(size_t)bh * DHD * DHD + idx] = s * isl_s[d];
    }
}

// ---------- M[b][c][he] = sum_d Wq[c][hd] * KVf[bh][d][e] * inv_scale ----------
__global__ __launch_bounds__(256) void m_kernel(const float* __restrict__ Wq,
                                                const float* __restrict__ KVf,
                                                float* __restrict__ M, float inv_scale)
{
    __shared__ float kvs[DHD * DHD];
    __shared__ float wqs[64][DHD];
    int h = blockIdx.x, b = blockIdx.y, t = threadIdx.x;
    for (int idx = t; idx < DHD * DHD; idx += 256)
        kvs[idx] = KVf[((size_t)(b * NH + h)) * DHD * DHD + idx];
    for (int c0 = 0; c0 < C1D; c0 += 64) {
        __syncthreads();
        for (int idx = t; idx < 64 * DHD; idx += 256) {
            int r = idx / DHD, d = idx % DHD;
            wqs[r][d] = Wq[(size_t)(c0 + r) * ADIM + h * DHD + d];
        }
        __syncthreads();
        for (int idx = t; idx < 64 * DHD; idx += 256) {
            int cl = idx / DHD, e = idx % DHD;
            float s = 0.f;
#pragma unroll
            for (int d = 0; d < DHD; ++d) s += wqs[cl][d] * kvs[d * DHD + e];
            M[((size_t)b * C1D + c0 + cl) * ADIM + h * DHD + e] = s * inv_scale;
        }
    }
}

// ---------- W_resT[b][c'][c] bf16 = sum_a Wo[a][c']*M[b][c][a] + (c==c') ----------
__global__ __launch_bounds__(256) void wres_kernel(const float* __restrict__ Wo,
                                                   const float* __restrict__ M,
                                                   unsigned short* __restrict__ WresT)
{
    __shared__ float Wos[16][64];
    __shared__ float Ms[64][17];
    int b = blockIdx.z;
    int m0 = blockIdx.x * 64;  // c'
    int n0 = blockIdx.y * 64;  // c
    int t = threadIdx.x;
    int tx = t & 15, ty = t >> 4;
    float acc[4][4] = {};
    for (int a0 = 0; a0 < ADIM; a0 += 16) {
#pragma unroll
        for (int i = 0; i < 4; ++i) {
            int idx = t + i * 256;
            int ka = idx >> 6, mm = idx & 63;
            Wos[ka][mm] = Wo[(size_t)(a0 + ka) * C1D + m0 + mm];
            int nn = idx >> 4, ka2 = idx & 15;
            Ms[nn][ka2] = M[((size_t)b * C1D + n0 + nn) * ADIM + a0 + ka2];
        }
        __syncthreads();
#pragma unroll
        for (int kc = 0; kc < 16; ++kc) {
            float mr[4], nr[4];
#pragma unroll
            for (int i = 0; i < 4; ++i) mr[i] = Wos[kc][ty * 4 + i];
#pragma unroll
            for (int j = 0; j < 4; ++j) nr[j] = Ms[tx * 4 + j][kc];
#pragma unroll
            for (int i = 0; i < 4; ++i)
#pragma unroll
                for (int j = 0; j < 4; ++j)
                    acc[i][j] += mr[i] * nr[j];
        }
        __syncthreads();
    }
#pragma unroll
    for (int i = 0; i < 4; ++i) {
        int cp = m0 + ty * 4 + i;
#pragma unroll
        for (int j = 0; j < 4; ++j) {
            int c = n0 + tx * 4 + j;
            float v = acc[i][j] + ((c == cp) ? 1.f : 0.f);
            WresT[((size_t)b * C1D + cp) * C1D + c] = f2bf(v);
        }
    }
}

// ---------- b_tot[b][c'] = sum_he (sum_d bq[hd]*KVf[h,d,e]*inv_scale) * Wo[he][c'] + bo[c'] ----------
__global__ __launch_bounds__(384) void btot_kernel(const float* __restrict__ bq,
                                                   const float* __restrict__ KVf,
                                                   const float* __restrict__ Wo,
                                                   const float* __restrict__ bo,
                                                   float* __restrict__ btot, float inv_scale)
{
    __shared__ float c0s[ADIM];
    int b = blockIdx.x, t = threadIdx.x;
    {
        int h = t / DHD, e = t % DHD;
        float s = 0.f;
#pragma unroll
        for (int d = 0; d < DHD; ++d)
            s += bq[h * DHD + d] * KVf[((size_t)(b * NH + h)) * DHD * DHD + d * DHD + e];
        c0s[t] = s * inv_scale;
    }
    __syncthreads();
    float bt = 0.f;
    for (int he = 0; he < ADIM; ++he) bt += c0s[he] * Wo[(size_t)he * C1D + t];
    btot[b * C1D + t] = bt + bo[t];
}

// ---------- b_tot add + LayerNorm + transpose store ----------
__global__ __launch_bounds__(256) void ln_store(const unsigned short* __restrict__ OUT,
                                                const float* __restrict__ btot,
                                                const float* __restrict__ gamma, const float* __restrict__ beta,
                                                float* __restrict__ Y)
{
    __shared__ float Ts[32][C1D + 1];
    __shared__ float mus[32], rss[32];
    int b = blockIdx.y, l0 = blockIdx.x * 32;
    int t = threadIdx.x;
    for (int idx = t; idx < 32 * C1D; idx += 256) {
        int li = idx / C1D, c = idx % C1D;
        Ts[li][c] = bf2f(OUT[(size_t)b * LDIM * C1D + (size_t)(l0 + li) * C1D + c]) + btot[b * C1D + c];
    }
    __syncthreads();
    {
        int li = t >> 3, sub = t & 7;
        float sm = 0.f, sq = 0.f;
        for (int c = sub; c < C1D; c += 8) { float v = Ts[li][c]; sm += v; sq += v * v; }
#pragma unroll
        for (int o = 1; o < 8; o <<= 1) { sm += __shfl_xor(sm, o, 64); sq += __shfl_xor(sq, o, 64); }
        if (sub == 0) {
            float mu = sm / C1D;
            float var = sq / C1D - mu * mu;
            mus[li] = mu;
            rss[li] = rsqrtf(var + LN_EPS);
        }
    }
    __syncthreads();
    for (int idx = t; idx < 32 * C1D; idx += 256) {
        int c = idx / 32, li = idx % 32;
        float v = (Ts[li][c] - mus[li]) * rss[li] * gamma[c] + beta[c];
        Y[(size_t)b * C1D * LDIM + (size_t)c * LDIM + l0 + li] = v;
    }
}

extern "C" void kernel_launch(void* const* d_in, const int* in_sizes, int n_in,
                              void* d_out, int out_size, void* d_ws, size_t ws_size,
                              hipStream_t stream) {
    const float* x1    = (const float*)d_in[0];
    const float* x2    = (const float*)d_in[1];
    const float* Wq    = (const float*)d_in[2];
    const float* bq    = (const float*)d_in[3];
    const float* Wk    = (const float*)d_in[4];
    const float* bk    = (const float*)d_in[5];
    const float* Wv    = (const float*)d_in[6];
    const float* bv    = (const float*)d_in[7];
    const float* Wo    = (const float*)d_in[8];
    const float* bo    = (const float*)d_in[9];
    const float* gamma = (const float*)d_in[10];
    const float* beta  = (const float*)d_in[11];
    float* out = (float*)d_out;

    char* p = (char*)d_ws;
    const size_t NB  = (size_t)BB * LDIM * ADIM;
    const size_t PBS = (size_t)LDIM * ADIM;    // per-batch stride
    unsigned short* X1p = (unsigned short*)p; p += NB * 2;
    unsigned short* X2p = (unsigned short*)p; p += NB;       // B*192*4096 elems = NB/2
    unsigned short* Kt  = (unsigned short*)p; p += NB * 2;
    unsigned short* Vt  = (unsigned short*)p; p += NB * 2;
    unsigned short* OUTb= (unsigned short*)p; p += NB * 2;
    unsigned short* Wkp = (unsigned short*)p; p += (size_t)C2D * ADIM * 2;
    unsigned short* Wvp = (unsigned short*)p; p += (size_t)C2D * ADIM * 2;
    float* kvpart = (float*)p; p += (size_t)BB * NH * KVLC * KVP_STRIDE * 4;
    float* KVf    = (float*)p; p += (size_t)BB * NH * DHD * DHD * 4;
    float* Mbuf   = (float*)p; p += (size_t)BB * C1D * ADIM * 4;
    unsigned short* WresT = (unsigned short*)p; p += (size_t)BB * C1D * C1D * 2;
    float* btot   = (float*)p; p += (size_t)BB * C1D * 4;

    float inv_scale = powf((float)DHD, -0.25f);

    transpose_cvt<<<dim3(LDIM / 32, C1D / 32, BB), 256, 0, stream>>>(x1, X1p, C1D, LDIM);
    transpose_cvt<<<dim3(LDIM / 32, C2D / 32, BB), 256, 0, stream>>>(x2, X2p, C2D, LDIM);
    transpose_cvt<<<dim3(ADIM / 32, C2D / 32, 1), 256, 0, stream>>>(Wk, Wkp, C2D, ADIM);
    transpose_cvt<<<dim3(ADIM / 32, C2D / 32, 1), 256, 0, stream>>>(Wv, Wvp, C2D, ADIM);

    // Kt[b,a,l], Vt[b,a,l]
    gemm_mfma<C2D, 2><<<dim3(ADIM / 128, LDIM / 128, BB), 256, 0, stream>>>(
        Wkp, 0, X2p, (size_t)LDIM * C2D, bk, Kt, PBS, LDIM, inv_scale);
    gemm_mfma<C2D, 2><<<dim3(ADIM / 128, LDIM / 128, BB), 256, 0, stream>>>(
        Wvp, 0, X2p, (size_t)LDIM * C2D, bv, Vt, PBS, LDIM, 1.0f);

    kv_part<<<dim3(KVLC, NH, BB), 64, 0, stream>>>(Kt, Vt, kvpart);
    kv_finalize<<<BB * NH, 256, 0, stream>>>(kvpart, KVf);

    m_kernel<<<dim3(NH, BB), 256, 0, stream>>>(Wq, KVf, Mbuf, inv_scale);
    wres_kernel<<<dim3(C1D / 64, C1D / 64, BB), 256, 0, stream>>>(Wo, Mbuf, WresT);
    btot_kernel<<<BB, 384, 0, stream>>>(bq, KVf, Wo, bo, btot, inv_scale);

    // OUT[b,l,c'] = x1f . W_res   (residual folded into W_res diagonal)
    gemm_mfma<C1D, 0><<<dim3(LDIM / 128, C1D / 128, BB), 256, 0, stream>>>(
        X1p, PBS, WresT, (size_t)C1D * C1D, bo /*unused*/, OUTb, PBS, C1D, 1.0f);

    ln_store<<<dim3(LDIM / 32, BB), 256, 0, stream>>>(OUTb, btot, gamma, beta, out);
}

// Round 7
// 186.184 us; speedup vs baseline: 1.3557x; 1.3557x over previous
//
#include <hip/hip_runtime.h>
#include <hip/hip_bf16.h>
#include <math.h>

#define BB 8
#define C1D 384
#define C2D 192
#define LDIM 4096
#define ADIM 384
#define NH 8
#define DHD 48
#define KVLC 16
#define KVP_STRIDE 2352   // 48*48 partials + 48 expsums
#define LN_EPS 1e-5f

typedef short s8v __attribute__((ext_vector_type(8)));
typedef float f4v __attribute__((ext_vector_type(4)));

__device__ __forceinline__ unsigned short f2bf(float f) {
    unsigned u = __builtin_bit_cast(unsigned, f);
    unsigned r = (u + 0x7FFFu + ((u >> 16) & 1u)) >> 16;
    return (unsigned short)r;
}
__device__ __forceinline__ float bf2f(unsigned short h) {
    unsigned u = ((unsigned)h) << 16;
    return __builtin_bit_cast(float, u);
}
__device__ __forceinline__ void gload16(const void* g, void* l) {
    __builtin_amdgcn_global_load_lds((const __attribute__((address_space(1))) void*)g,
                                     (__attribute__((address_space(3))) void*)l, 16, 0, 0);
}

// ---------- transpose fp32 [bz][R][Cols] -> bf16 [bz][Cols][R] ----------
__global__ __launch_bounds__(256) void transpose_cvt(const float* __restrict__ in,
                                                     unsigned short* __restrict__ out,
                                                     int R, int Cols)
{
    __shared__ float T[32][33];
    int b = blockIdx.z;
    int c0 = blockIdx.x * 32, r0 = blockIdx.y * 32;
    const float* ib = in + (size_t)b * R * Cols;
    unsigned short* ob = out + (size_t)b * R * Cols;
    int t = threadIdx.x;
#pragma unroll
    for (int i = 0; i < 4; ++i) {
        int idx = t + i * 256;
        int rr = idx >> 5, cc = idx & 31;
        T[rr][cc] = ib[(size_t)(r0 + rr) * Cols + c0 + cc];
    }
    __syncthreads();
#pragma unroll
    for (int i = 0; i < 2; ++i) {
        int idx = t + i * 256;
        int cc = idx >> 4, rp = (idx & 15) * 2;
        unsigned val = (unsigned)f2bf(T[rp][cc]) | ((unsigned)f2bf(T[rp + 1][cc]) << 16);
        *(unsigned*)&ob[(size_t)(c0 + cc) * R + r0 + rp] = val;
    }
}

// ---------- bf16 MFMA GEMM: Out[b,m,n] = scl*(sum_k A[b,m,k]*Bt[b,n,k] + bias) ----------
// BMODE: 0 = no bias, 1 = bias over n, 2 = bias over m
template<int KD, int BMODE>
__global__ __launch_bounds__(256) void gemm_mfma(
    const unsigned short* __restrict__ A, size_t Abs,
    const unsigned short* __restrict__ Bt, size_t Bbs,
    const float* __restrict__ bias,
    unsigned short* __restrict__ Out, size_t Obs, int Ncols, float scl)
{
    __shared__ unsigned short As[128 * 64];
    __shared__ unsigned short Bs[128 * 64];
    const int t = threadIdx.x;
    const int lane = t & 63;
    const int w = t >> 6;
    const int wm = w >> 1, wn = w & 1;
    const int b = blockIdx.z;
    const int m0 = blockIdx.x * 128;
    const int n0 = blockIdx.y * 128;

    const unsigned short* Ab = A + Abs * b + (size_t)m0 * KD;
    const unsigned short* Bb = Bt + Bbs * b + (size_t)n0 * KD;

    f4v acc[4][4];
#pragma unroll
    for (int i = 0; i < 4; ++i)
#pragma unroll
        for (int j = 0; j < 4; ++j) acc[i][j] = (f4v)0.f;

    const int r_l = lane >> 3;
    const int q = lane & 7;

    for (int ks = 0; ks < KD; ks += 64) {
#pragma unroll
        for (int c = 0; c < 4; ++c) {
            int row = w * 32 + c * 8 + r_l;
            int koff = ((q ^ (row & 7)) << 3);
            gload16(Ab + (size_t)row * KD + ks + koff, &As[(w * 32 + c * 8) * 64]);
            gload16(Bb + (size_t)row * KD + ks + koff, &Bs[(w * 32 + c * 8) * 64]);
        }
        __syncthreads();
#pragma unroll
        for (int kh = 0; kh < 2; ++kh) {
            s8v af[4], bfr[4];
            int kq = kh * 4 + (lane >> 4);
#pragma unroll
            for (int m = 0; m < 4; ++m) {
                int row = wm * 64 + m * 16 + (lane & 15);
                af[m] = *(const s8v*)&As[row * 64 + ((kq ^ (row & 7)) << 3)];
            }
#pragma unroll
            for (int n = 0; n < 4; ++n) {
                int row = wn * 64 + n * 16 + (lane & 15);
                bfr[n] = *(const s8v*)&Bs[row * 64 + ((kq ^ (row & 7)) << 3)];
            }
#pragma unroll
            for (int m = 0; m < 4; ++m)
#pragma unroll
                for (int n = 0; n < 4; ++n)
                    acc[m][n] = __builtin_amdgcn_mfma_f32_16x16x32_bf16(af[m], bfr[n], acc[m][n], 0, 0, 0);
        }
        __syncthreads();
    }

    float bn[4], bm[4][4];
    if (BMODE == 2) {
#pragma unroll
        for (int m = 0; m < 4; ++m)
#pragma unroll
            for (int r = 0; r < 4; ++r)
                bm[m][r] = bias[m0 + wm * 64 + m * 16 + (lane >> 4) * 4 + r];
    } else if (BMODE == 1) {
#pragma unroll
        for (int n = 0; n < 4; ++n) bn[n] = bias[n0 + wn * 64 + n * 16 + (lane & 15)];
    }
#pragma unroll
    for (int m = 0; m < 4; ++m)
#pragma unroll
        for (int n = 0; n < 4; ++n) {
            int col = n0 + wn * 64 + n * 16 + (lane & 15);
#pragma unroll
            for (int r = 0; r < 4; ++r) {
                int row = m0 + wm * 64 + m * 16 + (lane >> 4) * 4 + r;
                float bb = (BMODE == 2) ? bm[m][r] : (BMODE == 1) ? bn[n] : 0.f;
                float v = (acc[m][n][r] + bb) * scl;
                Out[Obs * b + (size_t)row * Ncols + col] = f2bf(v);
            }
        }
}

// ---------- kvpart[bh][lc][e*48+d] = partial sum_l Vt[e][l]*exp(Kt[d][l]); +expsums[d] ----------
__global__ __launch_bounds__(64) void kv_part(const unsigned short* __restrict__ Kt,
                                              const unsigned short* __restrict__ Vt,
                                              float* __restrict__ kvpart)
{
    int lane = threadIdx.x;
    int b = blockIdx.z, h = blockIdx.y, lc = blockIdx.x;
    size_t base = ((size_t)b * ADIM + h * DHD) * LDIM;
    const unsigned short* Kb = Kt + base;
    const unsigned short* Vb = Vt + base;
    int lbase = lc * (LDIM / KVLC);

    f4v acc[3][3];
#pragma unroll
    for (int i = 0; i < 3; ++i)
#pragma unroll
        for (int j = 0; j < 3; ++j) acc[i][j] = (f4v)0.f;
    float es[3] = {0.f, 0.f, 0.f};

    for (int ks = 0; ks < LDIM / KVLC; ks += 32) {
        int l0 = lbase + ks + ((lane >> 4) * 8);
        s8v af[3], bfr[3];
#pragma unroll
        for (int me = 0; me < 3; ++me)
            af[me] = *(const s8v*)&Vb[(size_t)(me * 16 + (lane & 15)) * LDIM + l0];
#pragma unroll
        for (int nd = 0; nd < 3; ++nd) {
            s8v raw = *(const s8v*)&Kb[(size_t)(nd * 16 + (lane & 15)) * LDIM + l0];
#pragma unroll
            for (int j = 0; j < 8; ++j) {
                float e = __expf(bf2f((unsigned short)raw[j]));
                es[nd] += e;
                bfr[nd][j] = (short)f2bf(e);
            }
        }
#pragma unroll
        for (int me = 0; me < 3; ++me)
#pragma unroll
            for (int nd = 0; nd < 3; ++nd)
                acc[me][nd] = __builtin_amdgcn_mfma_f32_16x16x32_bf16(af[me], bfr[nd], acc[me][nd], 0, 0, 0);
    }
    float* pp = kvpart + (((size_t)(b * NH + h) * KVLC) + lc) * KVP_STRIDE;
#pragma unroll
    for (int me = 0; me < 3; ++me)
#pragma unroll
        for (int nd = 0; nd < 3; ++nd)
#pragma unroll
            for (int r = 0; r < 4; ++r) {
                int e = me * 16 + (lane >> 4) * 4 + r;   // C/D row
                int d = nd * 16 + (lane & 15);           // C/D col
                pp[e * DHD + d] = acc[me][nd][r];
            }
#pragma unroll
    for (int nd = 0; nd < 3; ++nd) {
        float s = es[nd];
        s += __shfl_xor(s, 16, 64);
        s += __shfl_xor(s, 32, 64);
        if (lane < 16) pp[2304 + nd * 16 + lane] = s;
    }
}

// ---------- KVf[bh][d*48+e] = (sum_lc part[e][d]) / (sum_lc expsum[d]) ----------
__global__ __launch_bounds__(256) void kv_finalize(const float* __restrict__ kvpart,
                                                   float* __restrict__ KVf)
{
    __shared__ float isl_s[DHD];
    int bh = blockIdx.x, t = threadIdx.x;
    const float* pp = kvpart + (size_t)bh * KVLC * KVP_STRIDE;
    if (t < DHD) {
        float s = 0.f;
#pragma unroll
        for (int lc = 0; lc < KVLC; ++lc) s += pp[lc * KVP_STRIDE + 2304 + t];
        isl_s[t] = 1.f / s;
    }
    __syncthreads();
    for (int idx = t; idx < DHD * DHD; idx += 256) {
        int d = idx / DHD, e = idx % DHD;
        float s = 0.f;
#pragma unroll
        for (int lc = 0; lc < KVLC; ++lc) s += pp[lc * KVP_STRIDE + e * DHD + d];
        KVf[(size_t)bh * DHD * DHD + idx] = s * isl_s[d];
    }
}

// ---------- M[b][c][he] = sum_d Wq[c][hd] * KVf[bh][d][e] * inv_scale  (parallel) ----------
__global__ __launch_bounds__(256) void m_kernel(const float* __restrict__ Wq,
                                                const float* __restrict__ KVf,
                                                float* __restrict__ M, float inv_scale)
{
    __shared__ float kvs[DHD * DHD];
    int c0 = blockIdx.x * 64, h = blockIdx.y, b = blockIdx.z;
    int t = threadIdx.x;
    for (int idx = t; idx < DHD * DHD; idx += 256)
        kvs[idx] = KVf[((size_t)(b * NH + h)) * DHD * DHD + idx];
    __syncthreads();
    int cl = t >> 2, qq = t & 3;   // 64 rows x 4 column-quarters
    int c = c0 + cl;
    float wq[DHD];
#pragma unroll
    for (int d = 0; d < DHD; ++d) wq[d] = Wq[(size_t)c * ADIM + h * DHD + d];
    float s[12];
#pragma unroll
    for (int j = 0; j < 12; ++j) s[j] = 0.f;
#pragma unroll
    for (int d = 0; d < DHD; ++d) {
        float w = wq[d];
#pragma unroll
        for (int j = 0; j < 12; ++j)
            s[j] += w * kvs[d * DHD + qq * 12 + j];
    }
#pragma unroll
    for (int j = 0; j < 12; ++j)
        M[((size_t)b * C1D + c) * ADIM + h * DHD + qq * 12 + j] = s[j] * inv_scale;
}

// ---------- W_resT[b][c'][c] bf16 = sum_a Wo[a][c']*M[b][c][a] + (c==c') ----------
__global__ __launch_bounds__(256) void wres_kernel(const float* __restrict__ Wo,
                                                   const float* __restrict__ M,
                                                   unsigned short* __restrict__ WresT)
{
    __shared__ float Wos[16][64];
    __shared__ float Ms[64][17];
    int b = blockIdx.z;
    int m0 = blockIdx.x * 64;  // c'
    int n0 = blockIdx.y * 64;  // c
    int t = threadIdx.x;
    int tx = t & 15, ty = t >> 4;
    float acc[4][4] = {};
    for (int a0 = 0; a0 < ADIM; a0 += 16) {
#pragma unroll
        for (int i = 0; i < 4; ++i) {
            int idx = t + i * 256;
            int ka = idx >> 6, mm = idx & 63;
            Wos[ka][mm] = Wo[(size_t)(a0 + ka) * C1D + m0 + mm];
            int nn = idx >> 4, ka2 = idx & 15;
            Ms[nn][ka2] = M[((size_t)b * C1D + n0 + nn) * ADIM + a0 + ka2];
        }
        __syncthreads();
#pragma unroll
        for (int kc = 0; kc < 16; ++kc) {
            float mr[4], nr[4];
#pragma unroll
            for (int i = 0; i < 4; ++i) mr[i] = Wos[kc][ty * 4 + i];
#pragma unroll
            for (int j = 0; j < 4; ++j) nr[j] = Ms[tx * 4 + j][kc];
#pragma unroll
            for (int i = 0; i < 4; ++i)
#pragma unroll
                for (int j = 0; j < 4; ++j)
                    acc[i][j] += mr[i] * nr[j];
        }
        __syncthreads();
    }
#pragma unroll
    for (int i = 0; i < 4; ++i) {
        int cp = m0 + ty * 4 + i;
#pragma unroll
        for (int j = 0; j < 4; ++j) {
            int c = n0 + tx * 4 + j;
            float v = acc[i][j] + ((c == cp) ? 1.f : 0.f);
            WresT[((size_t)b * C1D + cp) * C1D + c] = f2bf(v);
        }
    }
}

// ---------- btot[b][c'] = sum_he c0s[he]*Wo[he][c'] + bo[c'] (parallel) ----------
__global__ __launch_bounds__(256) void btot_kernel(const float* __restrict__ bq,
                                                   const float* __restrict__ KVf,
                                                   const float* __restrict__ Wo,
                                                   const float* __restrict__ bo,
                                                   float* __restrict__ btot, float inv_scale)
{
    __shared__ float c0s[ADIM];
    int cp0 = blockIdx.x * 32, b = blockIdx.y, t = threadIdx.x;
    for (int idx = t; idx < ADIM; idx += 256) {
        int h = idx / DHD, e = idx % DHD;
        float s = 0.f;
#pragma unroll
        for (int d = 0; d < DHD; ++d)
            s += bq[h * DHD + d] * KVf[((size_t)(b * NH + h)) * DHD * DHD + d * DHD + e];
        c0s[idx] = s * inv_scale;
    }
    __syncthreads();
    int cp = cp0 + (t >> 3), part = t & 7;
    float s = 0.f;
#pragma unroll
    for (int i = 0; i < 48; ++i) {
        int he = part * 48 + i;
        s += c0s[he] * Wo[(size_t)he * C1D + cp];
    }
    s += __shfl_xor(s, 1, 64);
    s += __shfl_xor(s, 2, 64);
    s += __shfl_xor(s, 4, 64);
    if (part == 0) btot[b * C1D + cp] = s + bo[cp];
}

// ---------- b_tot add + LayerNorm + transpose store ----------
__global__ __launch_bounds__(256) void ln_store(const unsigned short* __restrict__ OUT,
                                                const float* __restrict__ btot,
                                                const float* __restrict__ gamma, const float* __restrict__ beta,
                                                float* __restrict__ Y)
{
    __shared__ float Ts[32][C1D + 1];
    __shared__ float mus[32], rss[32];
    int b = blockIdx.y, l0 = blockIdx.x * 32;
    int t = threadIdx.x;
    for (int idx = t; idx < 32 * C1D; idx += 256) {
        int li = idx / C1D, c = idx % C1D;
        Ts[li][c] = bf2f(OUT[(size_t)b * LDIM * C1D + (size_t)(l0 + li) * C1D + c]) + btot[b * C1D + c];
    }
    __syncthreads();
    {
        int li = t >> 3, sub = t & 7;
        float sm = 0.f, sq = 0.f;
        for (int c = sub; c < C1D; c += 8) { float v = Ts[li][c]; sm += v; sq += v * v; }
#pragma unroll
        for (int o = 1; o < 8; o <<= 1) { sm += __shfl_xor(sm, o, 64); sq += __shfl_xor(sq, o, 64); }
        if (sub == 0) {
            float mu = sm / C1D;
            float var = sq / C1D - mu * mu;
            mus[li] = mu;
            rss[li] = rsqrtf(var + LN_EPS);
        }
    }
    __syncthreads();
    for (int idx = t; idx < 32 * C1D; idx += 256) {
        int c = idx / 32, li = idx % 32;
        float v = (Ts[li][c] - mus[li]) * rss[li] * gamma[c] + beta[c];
        Y[(size_t)b * C1D * LDIM + (size_t)c * LDIM + l0 + li] = v;
    }
}

extern "C" void kernel_launch(void* const* d_in, const int* in_sizes, int n_in,
                              void* d_out, int out_size, void* d_ws, size_t ws_size,
                              hipStream_t stream) {
    const float* x1    = (const float*)d_in[0];
    const float* x2    = (const float*)d_in[1];
    const float* Wq    = (const float*)d_in[2];
    const float* bq    = (const float*)d_in[3];
    const float* Wk    = (const float*)d_in[4];
    const float* bk    = (const float*)d_in[5];
    const float* Wv    = (const float*)d_in[6];
    const float* bv    = (const float*)d_in[7];
    const float* Wo    = (const float*)d_in[8];
    const float* bo    = (const float*)d_in[9];
    const float* gamma = (const float*)d_in[10];
    const float* beta  = (const float*)d_in[11];
    float* out = (float*)d_out;

    char* p = (char*)d_ws;
    const size_t NB  = (size_t)BB * LDIM * ADIM;
    const size_t PBS = (size_t)LDIM * ADIM;    // per-batch stride
    unsigned short* X1p = (unsigned short*)p; p += NB * 2;
    unsigned short* X2p = (unsigned short*)p; p += NB;       // B*192*4096 elems = NB/2
    unsigned short* Kt  = (unsigned short*)p; p += NB * 2;
    unsigned short* Vt  = (unsigned short*)p; p += NB * 2;
    unsigned short* OUTb= (unsigned short*)p; p += NB * 2;
    unsigned short* Wkp = (unsigned short*)p; p += (size_t)C2D * ADIM * 2;
    unsigned short* Wvp = (unsigned short*)p; p += (size_t)C2D * ADIM * 2;
    float* kvpart = (float*)p; p += (size_t)BB * NH * KVLC * KVP_STRIDE * 4;
    float* KVf    = (float*)p; p += (size_t)BB * NH * DHD * DHD * 4;
    float* Mbuf   = (float*)p; p += (size_t)BB * C1D * ADIM * 4;
    unsigned short* WresT = (unsigned short*)p; p += (size_t)BB * C1D * C1D * 2;
    float* btot   = (float*)p; p += (size_t)BB * C1D * 4;

    float inv_scale = powf((float)DHD, -0.25f);

    transpose_cvt<<<dim3(LDIM / 32, C1D / 32, BB), 256, 0, stream>>>(x1, X1p, C1D, LDIM);
    transpose_cvt<<<dim3(LDIM / 32, C2D / 32, BB), 256, 0, stream>>>(x2, X2p, C2D, LDIM);
    transpose_cvt<<<dim3(ADIM / 32, C2D / 32, 1), 256, 0, stream>>>(Wk, Wkp, C2D, ADIM);
    transpose_cvt<<<dim3(ADIM / 32, C2D / 32, 1), 256, 0, stream>>>(Wv, Wvp, C2D, ADIM);

    // Kt[b,a,l], Vt[b,a,l]
    gemm_mfma<C2D, 2><<<dim3(ADIM / 128, LDIM / 128, BB), 256, 0, stream>>>(
        Wkp, 0, X2p, (size_t)LDIM * C2D, bk, Kt, PBS, LDIM, inv_scale);
    gemm_mfma<C2D, 2><<<dim3(ADIM / 128, LDIM / 128, BB), 256, 0, stream>>>(
        Wvp, 0, X2p, (size_t)LDIM * C2D, bv, Vt, PBS, LDIM, 1.0f);

    kv_part<<<dim3(KVLC, NH, BB), 64, 0, stream>>>(Kt, Vt, kvpart);
    kv_finalize<<<BB * NH, 256, 0, stream>>>(kvpart, KVf);

    m_kernel<<<dim3(C1D / 64, NH, BB), 256, 0, stream>>>(Wq, KVf, Mbuf, inv_scale);
    wres_kernel<<<dim3(C1D / 64, C1D / 64, BB), 256, 0, stream>>>(Wo, Mbuf, WresT);
    btot_kernel<<<dim3(C1D / 32, BB), 256, 0, stream>>>(bq, KVf, Wo, bo, btot, inv_scale);

    // OUT[b,l,c'] = x1f . W_res   (residual folded into W_res diagonal)
    gemm_mfma<C1D, 0><<<dim3(LDIM / 128, C1D / 128, BB), 256, 0, stream>>>(
        X1p, PBS, WresT, (size_t)C1D * C1D, bo /*unused*/, OUTb, PBS, C1D, 1.0f);

    ln_store<<<dim3(LDIM / 32, BB), 256, 0, stream>>>(OUTb, btot, gamma, beta, out);
}

// Round 8
// 157.840 us; speedup vs baseline: 1.5992x; 1.1796x over previous
//
#include <hip/hip_runtime.h>
#include <hip/hip_bf16.h>
#include <math.h>

#define BB 8
#define C1D 384
#define C2D 192
#define LDIM 4096
#define ADIM 384
#define NH 8
#define DHD 48
#define KVLC 16
#define KVP_STRIDE 2352   // 48*48 partials + 48 expsums
#define LN_EPS 1e-5f

typedef short s8v __attribute__((ext_vector_type(8)));
typedef float f4v __attribute__((ext_vector_type(4)));

__device__ __forceinline__ unsigned short f2bf(float f) {
    unsigned u = __builtin_bit_cast(unsigned, f);
    unsigned r = (u + 0x7FFFu + ((u >> 16) & 1u)) >> 16;
    return (unsigned short)r;
}
__device__ __forceinline__ float bf2f(unsigned short h) {
    unsigned u = ((unsigned)h) << 16;
    return __builtin_bit_cast(float, u);
}
__device__ __forceinline__ void gload16(const void* g, void* l) {
    __builtin_amdgcn_global_load_lds((const __attribute__((address_space(1))) void*)g,
                                     (__attribute__((address_space(3))) void*)l, 16, 0, 0);
}

// ---------- transpose fp32 [bz][R][Cols] -> bf16 [bz][Cols][R] ----------
__global__ __launch_bounds__(256) void transpose_cvt(const float* __restrict__ in,
                                                     unsigned short* __restrict__ out,
                                                     int R, int Cols)
{
    __shared__ float T[32][33];
    int b = blockIdx.z;
    int c0 = blockIdx.x * 32, r0 = blockIdx.y * 32;
    const float* ib = in + (size_t)b * R * Cols;
    unsigned short* ob = out + (size_t)b * R * Cols;
    int t = threadIdx.x;
#pragma unroll
    for (int i = 0; i < 4; ++i) {
        int idx = t + i * 256;
        int rr = idx >> 5, cc = idx & 31;
        T[rr][cc] = ib[(size_t)(r0 + rr) * Cols + c0 + cc];
    }
    __syncthreads();
#pragma unroll
    for (int i = 0; i < 2; ++i) {
        int idx = t + i * 256;
        int cc = idx >> 4, rp = (idx & 15) * 2;
        unsigned val = (unsigned)f2bf(T[rp][cc]) | ((unsigned)f2bf(T[rp + 1][cc]) << 16);
        *(unsigned*)&ob[(size_t)(c0 + cc) * R + r0 + rp] = val;
    }
}

// ---------- bf16 MFMA GEMM: Out[b,m,n] = scl*(sum_k A[b,m,k]*Bt[b,n,k] + bias) ----------
// BMODE: 0 = no bias, 1 = bias over n, 2 = bias over m, 3 = add identity (row==col)
template<int KD, int BMODE>
__global__ __launch_bounds__(256) void gemm_mfma(
    const unsigned short* __restrict__ A, size_t Abs,
    const unsigned short* __restrict__ Bt, size_t Bbs,
    const float* __restrict__ bias,
    unsigned short* __restrict__ Out, size_t Obs, int Ncols, float scl)
{
    __shared__ unsigned short As[128 * 64];
    __shared__ unsigned short Bs[128 * 64];
    const int t = threadIdx.x;
    const int lane = t & 63;
    const int w = t >> 6;
    const int wm = w >> 1, wn = w & 1;
    const int b = blockIdx.z;
    const int m0 = blockIdx.x * 128;
    const int n0 = blockIdx.y * 128;

    const unsigned short* Ab = A + Abs * b + (size_t)m0 * KD;
    const unsigned short* Bb = Bt + Bbs * b + (size_t)n0 * KD;

    f4v acc[4][4];
#pragma unroll
    for (int i = 0; i < 4; ++i)
#pragma unroll
        for (int j = 0; j < 4; ++j) acc[i][j] = (f4v)0.f;

    const int r_l = lane >> 3;
    const int q = lane & 7;

    for (int ks = 0; ks < KD; ks += 64) {
#pragma unroll
        for (int c = 0; c < 4; ++c) {
            int row = w * 32 + c * 8 + r_l;
            int koff = ((q ^ (row & 7)) << 3);
            gload16(Ab + (size_t)row * KD + ks + koff, &As[(w * 32 + c * 8) * 64]);
            gload16(Bb + (size_t)row * KD + ks + koff, &Bs[(w * 32 + c * 8) * 64]);
        }
        __syncthreads();
#pragma unroll
        for (int kh = 0; kh < 2; ++kh) {
            s8v af[4], bfr[4];
            int kq = kh * 4 + (lane >> 4);
#pragma unroll
            for (int m = 0; m < 4; ++m) {
                int row = wm * 64 + m * 16 + (lane & 15);
                af[m] = *(const s8v*)&As[row * 64 + ((kq ^ (row & 7)) << 3)];
            }
#pragma unroll
            for (int n = 0; n < 4; ++n) {
                int row = wn * 64 + n * 16 + (lane & 15);
                bfr[n] = *(const s8v*)&Bs[row * 64 + ((kq ^ (row & 7)) << 3)];
            }
#pragma unroll
            for (int m = 0; m < 4; ++m)
#pragma unroll
                for (int n = 0; n < 4; ++n)
                    acc[m][n] = __builtin_amdgcn_mfma_f32_16x16x32_bf16(af[m], bfr[n], acc[m][n], 0, 0, 0);
        }
        __syncthreads();
    }

    float bn[4], bm[4][4];
    if (BMODE == 2) {
#pragma unroll
        for (int m = 0; m < 4; ++m)
#pragma unroll
            for (int r = 0; r < 4; ++r)
                bm[m][r] = bias[m0 + wm * 64 + m * 16 + (lane >> 4) * 4 + r];
    } else if (BMODE == 1) {
#pragma unroll
        for (int n = 0; n < 4; ++n) bn[n] = bias[n0 + wn * 64 + n * 16 + (lane & 15)];
    }
#pragma unroll
    for (int m = 0; m < 4; ++m)
#pragma unroll
        for (int n = 0; n < 4; ++n) {
            int col = n0 + wn * 64 + n * 16 + (lane & 15);
#pragma unroll
            for (int r = 0; r < 4; ++r) {
                int row = m0 + wm * 64 + m * 16 + (lane >> 4) * 4 + r;
                float bb = (BMODE == 2) ? bm[m][r] : (BMODE == 1) ? bn[n] : 0.f;
                float v = (acc[m][n][r] + bb) * scl;
                if (BMODE == 3 && row == col) v += 1.f;
                Out[Obs * b + (size_t)row * Ncols + col] = f2bf(v);
            }
        }
}

// ---------- kvpart[bh][lc][e*48+d] = partial sum_l Vt[e][l]*exp(Kt[d][l]); +expsums[d] ----------
__global__ __launch_bounds__(64) void kv_part(const unsigned short* __restrict__ Kt,
                                              const unsigned short* __restrict__ Vt,
                                              float* __restrict__ kvpart)
{
    int lane = threadIdx.x;
    int b = blockIdx.z, h = blockIdx.y, lc = blockIdx.x;
    size_t base = ((size_t)b * ADIM + h * DHD) * LDIM;
    const unsigned short* Kb = Kt + base;
    const unsigned short* Vb = Vt + base;
    int lbase = lc * (LDIM / KVLC);

    f4v acc[3][3];
#pragma unroll
    for (int i = 0; i < 3; ++i)
#pragma unroll
        for (int j = 0; j < 3; ++j) acc[i][j] = (f4v)0.f;
    float es[3] = {0.f, 0.f, 0.f};

    for (int ks = 0; ks < LDIM / KVLC; ks += 32) {
        int l0 = lbase + ks + ((lane >> 4) * 8);
        s8v af[3], bfr[3];
#pragma unroll
        for (int me = 0; me < 3; ++me)
            af[me] = *(const s8v*)&Vb[(size_t)(me * 16 + (lane & 15)) * LDIM + l0];
#pragma unroll
        for (int nd = 0; nd < 3; ++nd) {
            s8v raw = *(const s8v*)&Kb[(size_t)(nd * 16 + (lane & 15)) * LDIM + l0];
#pragma unroll
            for (int j = 0; j < 8; ++j) {
                float e = __expf(bf2f((unsigned short)raw[j]));
                es[nd] += e;
                bfr[nd][j] = (short)f2bf(e);
            }
        }
#pragma unroll
        for (int me = 0; me < 3; ++me)
#pragma unroll
            for (int nd = 0; nd < 3; ++nd)
                acc[me][nd] = __builtin_amdgcn_mfma_f32_16x16x32_bf16(af[me], bfr[nd], acc[me][nd], 0, 0, 0);
    }
    float* pp = kvpart + (((size_t)(b * NH + h) * KVLC) + lc) * KVP_STRIDE;
#pragma unroll
    for (int me = 0; me < 3; ++me)
#pragma unroll
        for (int nd = 0; nd < 3; ++nd)
#pragma unroll
            for (int r = 0; r < 4; ++r) {
                int e = me * 16 + (lane >> 4) * 4 + r;   // C/D row
                int d = nd * 16 + (lane & 15);           // C/D col
                pp[e * DHD + d] = acc[me][nd][r];
            }
#pragma unroll
    for (int nd = 0; nd < 3; ++nd) {
        float s = es[nd];
        s += __shfl_xor(s, 16, 64);
        s += __shfl_xor(s, 32, 64);
        if (lane < 16) pp[2304 + nd * 16 + lane] = s;
    }
}

// ---------- KVf[bh][d*48+e] = (sum_lc part[e][d]) / (sum_lc expsum[d]) ----------
__global__ __launch_bounds__(256) void kv_finalize(const float* __restrict__ kvpart,
                                                   float* __restrict__ KVf)
{
    __shared__ float isl_s[DHD];
    int bh = blockIdx.x, t = threadIdx.x;
    const float* pp = kvpart + (size_t)bh * KVLC * KVP_STRIDE;
    if (t < DHD) {
        float s = 0.f;
#pragma unroll
        for (int lc = 0; lc < KVLC; ++lc) s += pp[lc * KVP_STRIDE + 2304 + t];
        isl_s[t] = 1.f / s;
    }
    __syncthreads();
    for (int idx = t; idx < DHD * DHD; idx += 256) {
        int d = idx / DHD, e = idx % DHD;
        float s = 0.f;
#pragma unroll
        for (int lc = 0; lc < KVLC; ++lc) s += pp[lc * KVP_STRIDE + e * DHD + d];
        KVf[(size_t)bh * DHD * DHD + idx] = s * isl_s[d];
    }
}

// ---------- M[b][c][he] bf16 = sum_d Wq[c][hd] * KVf[bh][d][e] * inv_scale ----------
__global__ __launch_bounds__(256) void m_kernel(const float* __restrict__ Wq,
                                                const float* __restrict__ KVf,
                                                unsigned short* __restrict__ M, float inv_scale)
{
    __shared__ float kvs[DHD * DHD];
    int c0 = blockIdx.x * 64, h = blockIdx.y, b = blockIdx.z;
    int t = threadIdx.x;
    for (int idx = t; idx < DHD * DHD; idx += 256)
        kvs[idx] = KVf[((size_t)(b * NH + h)) * DHD * DHD + idx];
    __syncthreads();
    int cl = t >> 2, qq = t & 3;   // 64 rows x 4 column-quarters
    int c = c0 + cl;
    float wq[DHD];
#pragma unroll
    for (int d = 0; d < DHD; ++d) wq[d] = Wq[(size_t)c * ADIM + h * DHD + d];
    float s[12];
#pragma unroll
    for (int j = 0; j < 12; ++j) s[j] = 0.f;
#pragma unroll
    for (int d = 0; d < DHD; ++d) {
        float w = wq[d];
#pragma unroll
        for (int j = 0; j < 12; ++j)
            s[j] += w * kvs[d * DHD + qq * 12 + j];
    }
#pragma unroll
    for (int j = 0; j < 12; ++j)
        M[((size_t)b * C1D + c) * ADIM + h * DHD + qq * 12 + j] = f2bf(s[j] * inv_scale);
}

// ---------- btot[b][c'] = sum_he c0s[he]*Wo[he][c'] + bo[c'] (parallel) ----------
__global__ __launch_bounds__(256) void btot_kernel(const float* __restrict__ bq,
                                                   const float* __restrict__ KVf,
                                                   const float* __restrict__ Wo,
                                                   const float* __restrict__ bo,
                                                   float* __restrict__ btot, float inv_scale)
{
    __shared__ float c0s[ADIM];
    int cp0 = blockIdx.x * 32, b = blockIdx.y, t = threadIdx.x;
    for (int idx = t; idx < ADIM; idx += 256) {
        int h = idx / DHD, e = idx % DHD;
        float s = 0.f;
#pragma unroll
        for (int d = 0; d < DHD; ++d)
            s += bq[h * DHD + d] * KVf[((size_t)(b * NH + h)) * DHD * DHD + d * DHD + e];
        c0s[idx] = s * inv_scale;
    }
    __syncthreads();
    int cp = cp0 + (t >> 3), part = t & 7;
    float s = 0.f;
#pragma unroll
    for (int i = 0; i < 48; ++i) {
        int he = part * 48 + i;
        s += c0s[he] * Wo[(size_t)he * C1D + cp];
    }
    s += __shfl_xor(s, 1, 64);
    s += __shfl_xor(s, 2, 64);
    s += __shfl_xor(s, 4, 64);
    if (part == 0) btot[b * C1D + cp] = s + bo[cp];
}

// ---------- b_tot add + LayerNorm + transpose store ----------
__global__ __launch_bounds__(256) void ln_store(const unsigned short* __restrict__ OUT,
                                                const float* __restrict__ btot,
                                                const float* __restrict__ gamma, const float* __restrict__ beta,
                                                float* __restrict__ Y)
{
    __shared__ float Ts[32][C1D + 1];
    __shared__ float mus[32], rss[32];
    int b = blockIdx.y, l0 = blockIdx.x * 32;
    int t = threadIdx.x;
    for (int idx = t; idx < 32 * C1D; idx += 256) {
        int li = idx / C1D, c = idx % C1D;
        Ts[li][c] = bf2f(OUT[(size_t)b * LDIM * C1D + (size_t)(l0 + li) * C1D + c]) + btot[b * C1D + c];
    }
    __syncthreads();
    {
        int li = t >> 3, sub = t & 7;
        float sm = 0.f, sq = 0.f;
        for (int c = sub; c < C1D; c += 8) { float v = Ts[li][c]; sm += v; sq += v * v; }
#pragma unroll
        for (int o = 1; o < 8; o <<= 1) { sm += __shfl_xor(sm, o, 64); sq += __shfl_xor(sq, o, 64); }
        if (sub == 0) {
            float mu = sm / C1D;
            float var = sq / C1D - mu * mu;
            mus[li] = mu;
            rss[li] = rsqrtf(var + LN_EPS);
        }
    }
    __syncthreads();
    for (int idx = t; idx < 32 * C1D; idx += 256) {
        int c = idx / 32, li = idx % 32;
        float v = (Ts[li][c] - mus[li]) * rss[li] * gamma[c] + beta[c];
        Y[(size_t)b * C1D * LDIM + (size_t)c * LDIM + l0 + li] = v;
    }
}

extern "C" void kernel_launch(void* const* d_in, const int* in_sizes, int n_in,
                              void* d_out, int out_size, void* d_ws, size_t ws_size,
                              hipStream_t stream) {
    const float* x1    = (const float*)d_in[0];
    const float* x2    = (const float*)d_in[1];
    const float* Wq    = (const float*)d_in[2];
    const float* bq    = (const float*)d_in[3];
    const float* Wk    = (const float*)d_in[4];
    const float* bk    = (const float*)d_in[5];
    const float* Wv    = (const float*)d_in[6];
    const float* bv    = (const float*)d_in[7];
    const float* Wo    = (const float*)d_in[8];
    const float* bo    = (const float*)d_in[9];
    const float* gamma = (const float*)d_in[10];
    const float* beta  = (const float*)d_in[11];
    float* out = (float*)d_out;

    char* p = (char*)d_ws;
    const size_t NB  = (size_t)BB * LDIM * ADIM;
    const size_t PBS = (size_t)LDIM * ADIM;    // per-batch stride
    unsigned short* X1p = (unsigned short*)p; p += NB * 2;
    unsigned short* X2p = (unsigned short*)p; p += NB;       // B*192*4096 elems = NB/2
    unsigned short* Kt  = (unsigned short*)p; p += NB * 2;
    unsigned short* Vt  = (unsigned short*)p; p += NB * 2;
    unsigned short* OUTb= (unsigned short*)p; p += NB * 2;
    unsigned short* Wkp = (unsigned short*)p; p += (size_t)C2D * ADIM * 2;
    unsigned short* Wvp = (unsigned short*)p; p += (size_t)C2D * ADIM * 2;
    unsigned short* WoTp= (unsigned short*)p; p += (size_t)C1D * ADIM * 2;
    float* kvpart = (float*)p; p += (size_t)BB * NH * KVLC * KVP_STRIDE * 4;
    float* KVf    = (float*)p; p += (size_t)BB * NH * DHD * DHD * 4;
    unsigned short* Mbuf = (unsigned short*)p; p += (size_t)BB * C1D * ADIM * 2;
    unsigned short* WresT = (unsigned short*)p; p += (size_t)BB * C1D * C1D * 2;
    float* btot   = (float*)p; p += (size_t)BB * C1D * 4;

    float inv_scale = powf((float)DHD, -0.25f);

    transpose_cvt<<<dim3(LDIM / 32, C1D / 32, BB), 256, 0, stream>>>(x1, X1p, C1D, LDIM);
    transpose_cvt<<<dim3(LDIM / 32, C2D / 32, BB), 256, 0, stream>>>(x2, X2p, C2D, LDIM);
    transpose_cvt<<<dim3(ADIM / 32, C2D / 32, 1), 256, 0, stream>>>(Wk, Wkp, C2D, ADIM);
    transpose_cvt<<<dim3(ADIM / 32, C2D / 32, 1), 256, 0, stream>>>(Wv, Wvp, C2D, ADIM);
    transpose_cvt<<<dim3(C1D / 32, ADIM / 32, 1), 256, 0, stream>>>(Wo, WoTp, ADIM, C1D);

    // Kt[b,a,l], Vt[b,a,l]
    gemm_mfma<C2D, 2><<<dim3(ADIM / 128, LDIM / 128, BB), 256, 0, stream>>>(
        Wkp, 0, X2p, (size_t)LDIM * C2D, bk, Kt, PBS, LDIM, inv_scale);
    gemm_mfma<C2D, 2><<<dim3(ADIM / 128, LDIM / 128, BB), 256, 0, stream>>>(
        Wvp, 0, X2p, (size_t)LDIM * C2D, bv, Vt, PBS, LDIM, 1.0f);

    kv_part<<<dim3(KVLC, NH, BB), 64, 0, stream>>>(Kt, Vt, kvpart);
    kv_finalize<<<BB * NH, 256, 0, stream>>>(kvpart, KVf);

    m_kernel<<<dim3(C1D / 64, NH, BB), 256, 0, stream>>>(Wq, KVf, Mbuf, inv_scale);
    // W_resT[b][c'][c] = sum_a WoT[c'][a] * M[b][c][a] + (c'==c)   (MFMA)
    gemm_mfma<ADIM, 3><<<dim3(C1D / 128, C1D / 128, BB), 256, 0, stream>>>(
        WoTp, 0, Mbuf, (size_t)C1D * ADIM, bo /*unused*/, WresT, (size_t)C1D * C1D, C1D, 1.0f);
    btot_kernel<<<dim3(C1D / 32, BB), 256, 0, stream>>>(bq, KVf, Wo, bo, btot, inv_scale);

    // OUT[b,l,c'] = x1f . W_res   (residual folded into W_res diagonal)
    gemm_mfma<C1D, 0><<<dim3(LDIM / 128, C1D / 128, BB), 256, 0, stream>>>(
        X1p, PBS, WresT, (size_t)C1D * C1D, bo /*unused*/, OUTb, PBS, C1D, 1.0f);

    ln_store<<<dim3(LDIM / 32, BB), 256, 0, stream>>>(OUTb, btot, gamma, beta, out);
}

// Round 9
// 142.741 us; speedup vs baseline: 1.7683x; 1.1058x over previous
//
#include <hip/hip_runtime.h>
#include <hip/hip_bf16.h>
#include <math.h>

#define BB 8
#define C1D 384
#define C2D 192
#define LDIM 4096
#define ADIM 384
#define NH 8
#define DHD 48
#define KVLC 16
#define KVP_STRIDE 2352   // 48*48 partials + 48 expsums
#define LN_EPS 1e-5f

typedef short s8v __attribute__((ext_vector_type(8)));
typedef float f4v __attribute__((ext_vector_type(4)));

__device__ __forceinline__ unsigned short f2bf(float f) {
    unsigned u = __builtin_bit_cast(unsigned, f);
    unsigned r = (u + 0x7FFFu + ((u >> 16) & 1u)) >> 16;
    return (unsigned short)r;
}
__device__ __forceinline__ float bf2f(unsigned short h) {
    unsigned u = ((unsigned)h) << 16;
    return __builtin_bit_cast(float, u);
}
__device__ __forceinline__ void gload16(const void* g, void* l) {
    __builtin_amdgcn_global_load_lds((const __attribute__((address_space(1))) void*)g,
                                     (__attribute__((address_space(3))) void*)l, 16, 0, 0);
}

// ---------- transpose fp32 [bz][R][Cols] -> bf16 [bz][Cols][R] ----------
__global__ __launch_bounds__(256) void transpose_cvt(const float* __restrict__ in,
                                                     unsigned short* __restrict__ out,
                                                     int R, int Cols)
{
    __shared__ float T[32][33];
    int b = blockIdx.z;
    int c0 = blockIdx.x * 32, r0 = blockIdx.y * 32;
    const float* ib = in + (size_t)b * R * Cols;
    unsigned short* ob = out + (size_t)b * R * Cols;
    int t = threadIdx.x;
#pragma unroll
    for (int i = 0; i < 4; ++i) {
        int idx = t + i * 256;
        int rr = idx >> 5, cc = idx & 31;
        T[rr][cc] = ib[(size_t)(r0 + rr) * Cols + c0 + cc];
    }
    __syncthreads();
#pragma unroll
    for (int i = 0; i < 2; ++i) {
        int idx = t + i * 256;
        int cc = idx >> 4, rp = (idx & 15) * 2;
        unsigned val = (unsigned)f2bf(T[rp][cc]) | ((unsigned)f2bf(T[rp + 1][cc]) << 16);
        *(unsigned*)&ob[(size_t)(c0 + cc) * R + r0 + rp] = val;
    }
}

// ---------- bf16 MFMA GEMM: Out[b,m,n] = scl*(sum_k A[b,m,k]*Bt[b,n,k] + bias) ----------
// BMODE: 0 = no bias, 1 = bias over n, 2 = bias over m, 3 = add identity (row==col)
template<int KD, int BMODE>
__global__ __launch_bounds__(256) void gemm_mfma(
    const unsigned short* __restrict__ A, size_t Abs,
    const unsigned short* __restrict__ Bt, size_t Bbs,
    const float* __restrict__ bias,
    unsigned short* __restrict__ Out, size_t Obs, int Ncols, float scl)
{
    __shared__ unsigned short As[128 * 64];
    __shared__ unsigned short Bs[128 * 64];
    const int t = threadIdx.x;
    const int lane = t & 63;
    const int w = t >> 6;
    const int wm = w >> 1, wn = w & 1;
    const int b = blockIdx.z;
    const int m0 = blockIdx.x * 128;
    const int n0 = blockIdx.y * 128;

    const unsigned short* Ab = A + Abs * b + (size_t)m0 * KD;
    const unsigned short* Bb = Bt + Bbs * b + (size_t)n0 * KD;

    f4v acc[4][4];
#pragma unroll
    for (int i = 0; i < 4; ++i)
#pragma unroll
        for (int j = 0; j < 4; ++j) acc[i][j] = (f4v)0.f;

    const int r_l = lane >> 3;
    const int q = lane & 7;

    for (int ks = 0; ks < KD; ks += 64) {
#pragma unroll
        for (int c = 0; c < 4; ++c) {
            int row = w * 32 + c * 8 + r_l;
            int koff = ((q ^ (row & 7)) << 3);
            gload16(Ab + (size_t)row * KD + ks + koff, &As[(w * 32 + c * 8) * 64]);
            gload16(Bb + (size_t)row * KD + ks + koff, &Bs[(w * 32 + c * 8) * 64]);
        }
        __syncthreads();
#pragma unroll
        for (int kh = 0; kh < 2; ++kh) {
            s8v af[4], bfr[4];
            int kq = kh * 4 + (lane >> 4);
#pragma unroll
            for (int m = 0; m < 4; ++m) {
                int row = wm * 64 + m * 16 + (lane & 15);
                af[m] = *(const s8v*)&As[row * 64 + ((kq ^ (row & 7)) << 3)];
            }
#pragma unroll
            for (int n = 0; n < 4; ++n) {
                int row = wn * 64 + n * 16 + (lane & 15);
                bfr[n] = *(const s8v*)&Bs[row * 64 + ((kq ^ (row & 7)) << 3)];
            }
#pragma unroll
            for (int m = 0; m < 4; ++m)
#pragma unroll
                for (int n = 0; n < 4; ++n)
                    acc[m][n] = __builtin_amdgcn_mfma_f32_16x16x32_bf16(af[m], bfr[n], acc[m][n], 0, 0, 0);
        }
        __syncthreads();
    }

    float bn[4], bm[4][4];
    if (BMODE == 2) {
#pragma unroll
        for (int m = 0; m < 4; ++m)
#pragma unroll
            for (int r = 0; r < 4; ++r)
                bm[m][r] = bias[m0 + wm * 64 + m * 16 + (lane >> 4) * 4 + r];
    } else if (BMODE == 1) {
#pragma unroll
        for (int n = 0; n < 4; ++n) bn[n] = bias[n0 + wn * 64 + n * 16 + (lane & 15)];
    }
#pragma unroll
    for (int m = 0; m < 4; ++m)
#pragma unroll
        for (int n = 0; n < 4; ++n) {
            int col = n0 + wn * 64 + n * 16 + (lane & 15);
#pragma unroll
            for (int r = 0; r < 4; ++r) {
                int row = m0 + wm * 64 + m * 16 + (lane >> 4) * 4 + r;
                float bb = (BMODE == 2) ? bm[m][r] : (BMODE == 1) ? bn[n] : 0.f;
                float v = (acc[m][n][r] + bb) * scl;
                if (BMODE == 3 && row == col) v += 1.f;
                Out[Obs * b + (size_t)row * Ncols + col] = f2bf(v);
            }
        }
}

// ---------- kvpart[bh][lc][e*48+d] = partial sum_l Vt[e][l]*exp(Kt[d][l]); +expsums[d] ----------
__global__ __launch_bounds__(64) void kv_part(const unsigned short* __restrict__ Kt,
                                              const unsigned short* __restrict__ Vt,
                                              float* __restrict__ kvpart)
{
    int lane = threadIdx.x;
    int b = blockIdx.z, h = blockIdx.y, lc = blockIdx.x;
    size_t base = ((size_t)b * ADIM + h * DHD) * LDIM;
    const unsigned short* Kb = Kt + base;
    const unsigned short* Vb = Vt + base;
    int lbase = lc * (LDIM / KVLC);

    f4v acc[3][3];
#pragma unroll
    for (int i = 0; i < 3; ++i)
#pragma unroll
        for (int j = 0; j < 3; ++j) acc[i][j] = (f4v)0.f;
    float es[3] = {0.f, 0.f, 0.f};

    for (int ks = 0; ks < LDIM / KVLC; ks += 32) {
        int l0 = lbase + ks + ((lane >> 4) * 8);
        s8v af[3], bfr[3];
#pragma unroll
        for (int me = 0; me < 3; ++me)
            af[me] = *(const s8v*)&Vb[(size_t)(me * 16 + (lane & 15)) * LDIM + l0];
#pragma unroll
        for (int nd = 0; nd < 3; ++nd) {
            s8v raw = *(const s8v*)&Kb[(size_t)(nd * 16 + (lane & 15)) * LDIM + l0];
#pragma unroll
            for (int j = 0; j < 8; ++j) {
                float e = __expf(bf2f((unsigned short)raw[j]));
                es[nd] += e;
                bfr[nd][j] = (short)f2bf(e);
            }
        }
#pragma unroll
        for (int me = 0; me < 3; ++me)
#pragma unroll
            for (int nd = 0; nd < 3; ++nd)
                acc[me][nd] = __builtin_amdgcn_mfma_f32_16x16x32_bf16(af[me], bfr[nd], acc[me][nd], 0, 0, 0);
    }
    float* pp = kvpart + (((size_t)(b * NH + h) * KVLC) + lc) * KVP_STRIDE;
#pragma unroll
    for (int me = 0; me < 3; ++me)
#pragma unroll
        for (int nd = 0; nd < 3; ++nd)
#pragma unroll
            for (int r = 0; r < 4; ++r) {
                int e = me * 16 + (lane >> 4) * 4 + r;   // C/D row
                int d = nd * 16 + (lane & 15);           // C/D col
                pp[e * DHD + d] = acc[me][nd][r];
            }
#pragma unroll
    for (int nd = 0; nd < 3; ++nd) {
        float s = es[nd];
        s += __shfl_xor(s, 16, 64);
        s += __shfl_xor(s, 32, 64);
        if (lane < 16) pp[2304 + nd * 16 + lane] = s;
    }
}

// ---------- KVf[bh][d*48+e] = (sum_lc part[e][d]) / (sum_lc expsum[d]) ----------
__global__ __launch_bounds__(256) void kv_finalize(const float* __restrict__ kvpart,
                                                   float* __restrict__ KVf)
{
    __shared__ float isl_s[DHD];
    int bh = blockIdx.x, t = threadIdx.x;
    const float* pp = kvpart + (size_t)bh * KVLC * KVP_STRIDE;
    if (t < DHD) {
        float s = 0.f;
#pragma unroll
        for (int lc = 0; lc < KVLC; ++lc) s += pp[lc * KVP_STRIDE + 2304 + t];
        isl_s[t] = 1.f / s;
    }
    __syncthreads();
    for (int idx = t; idx < DHD * DHD; idx += 256) {
        int d = idx / DHD, e = idx % DHD;
        float s = 0.f;
#pragma unroll
        for (int lc = 0; lc < KVLC; ++lc) s += pp[lc * KVP_STRIDE + e * DHD + d];
        KVf[(size_t)bh * DHD * DHD + idx] = s * isl_s[d];
    }
}

// ---------- M[b][c][he] bf16 = sum_d Wq[c][hd] * KVf[bh][d][e] * inv_scale ----------
__global__ __launch_bounds__(256) void m_kernel(const float* __restrict__ Wq,
                                                const float* __restrict__ KVf,
                                                unsigned short* __restrict__ M, float inv_scale)
{
    __shared__ float kvs[DHD * DHD];
    int c0 = blockIdx.x * 64, h = blockIdx.y, b = blockIdx.z;
    int t = threadIdx.x;
    for (int idx = t; idx < DHD * DHD; idx += 256)
        kvs[idx] = KVf[((size_t)(b * NH + h)) * DHD * DHD + idx];
    __syncthreads();
    int cl = t >> 2, qq = t & 3;   // 64 rows x 4 column-quarters
    int c = c0 + cl;
    float wq[DHD];
#pragma unroll
    for (int d = 0; d < DHD; ++d) wq[d] = Wq[(size_t)c * ADIM + h * DHD + d];
    float s[12];
#pragma unroll
    for (int j = 0; j < 12; ++j) s[j] = 0.f;
#pragma unroll
    for (int d = 0; d < DHD; ++d) {
        float w = wq[d];
#pragma unroll
        for (int j = 0; j < 12; ++j)
            s[j] += w * kvs[d * DHD + qq * 12 + j];
    }
#pragma unroll
    for (int j = 0; j < 12; ++j)
        M[((size_t)b * C1D + c) * ADIM + h * DHD + qq * 12 + j] = f2bf(s[j] * inv_scale);
}

// ---------- btot[b][c'] = sum_he c0s[he]*Wo[he][c'] + bo[c'] (parallel) ----------
__global__ __launch_bounds__(256) void btot_kernel(const float* __restrict__ bq,
                                                   const float* __restrict__ KVf,
                                                   const float* __restrict__ Wo,
                                                   const float* __restrict__ bo,
                                                   float* __restrict__ btot, float inv_scale)
{
    __shared__ float c0s[ADIM];
    int cp0 = blockIdx.x * 32, b = blockIdx.y, t = threadIdx.x;
    for (int idx = t; idx < ADIM; idx += 256) {
        int h = idx / DHD, e = idx % DHD;
        float s = 0.f;
#pragma unroll
        for (int d = 0; d < DHD; ++d)
            s += bq[h * DHD + d] * KVf[((size_t)(b * NH + h)) * DHD * DHD + d * DHD + e];
        c0s[idx] = s * inv_scale;
    }
    __syncthreads();
    int cp = cp0 + (t >> 3), part = t & 7;
    float s = 0.f;
#pragma unroll
    for (int i = 0; i < 48; ++i) {
        int he = part * 48 + i;
        s += c0s[he] * Wo[(size_t)he * C1D + cp];
    }
    s += __shfl_xor(s, 1, 64);
    s += __shfl_xor(s, 2, 64);
    s += __shfl_xor(s, 4, 64);
    if (part == 0) btot[b * C1D + cp] = s + bo[cp];
}

// ---------- fused: OUT[b,l,c] = x1f . W_res; += btot; LayerNorm over c; store Y[b][c][l] ----------
// tile: 128 rows (l) x 384 cols (all channels); 8 waves (2 wrow x 4 wcol); BK=64
__global__ __launch_bounds__(512) void gemm_ln(
    const unsigned short* __restrict__ A,     // X1p [b][4096][384]
    const unsigned short* __restrict__ Bt,    // WresT [b][384][384]
    const float* __restrict__ btot,
    const float* __restrict__ gamma,
    const float* __restrict__ beta,
    float* __restrict__ Y)                    // [b][384][4096]
{
    __shared__ __align__(16) char lds[65536];
    unsigned short* As = (unsigned short*)lds;                 // [128][64] bf16
    unsigned short* Bs = (unsigned short*)(lds + 16384);       // [384][64] bf16
    float* stats = (float*)lds;                                // [128][4][2] (after K-loop)
    float* T = (float*)(lds + 8192);                           // [96][132]

    const int t = threadIdx.x;
    const int lane = t & 63;
    const int w = t >> 6;           // 0..7
    const int wrow = w >> 2, wcol = w & 3;
    const int b = blockIdx.z;
    const int l0 = blockIdx.x * 128;

    const unsigned short* Ab = A + ((size_t)b * LDIM + l0) * C1D;
    const unsigned short* Bb = Bt + (size_t)b * C1D * C1D;

    f4v acc[4][6];
#pragma unroll
    for (int m = 0; m < 4; ++m)
#pragma unroll
        for (int n = 0; n < 6; ++n) acc[m][n] = (f4v)0.f;

    const int r_l = lane >> 3;
    const int q = lane & 7;

    for (int ks = 0; ks < C1D; ks += 64) {
#pragma unroll
        for (int c = 0; c < 2; ++c) {
            int row = w * 16 + c * 8 + r_l;
            int koff = ((q ^ (row & 7)) << 3);
            gload16(Ab + (size_t)row * C1D + ks + koff, &As[(w * 16 + c * 8) * 64]);
        }
#pragma unroll
        for (int c = 0; c < 6; ++c) {
            int row = w * 48 + c * 8 + r_l;
            int koff = ((q ^ (row & 7)) << 3);
            gload16(Bb + (size_t)row * C1D + ks + koff, &Bs[(w * 48 + c * 8) * 64]);
        }
        __syncthreads();
#pragma unroll
        for (int kh = 0; kh < 2; ++kh) {
            int kq = kh * 4 + (lane >> 4);
            s8v af[4], bfr[6];
#pragma unroll
            for (int m = 0; m < 4; ++m) {
                int row = wrow * 64 + m * 16 + (lane & 15);
                af[m] = *(const s8v*)&As[row * 64 + ((kq ^ (row & 7)) << 3)];
            }
#pragma unroll
            for (int n = 0; n < 6; ++n) {
                int row = wcol * 96 + n * 16 + (lane & 15);
                bfr[n] = *(const s8v*)&Bs[row * 64 + ((kq ^ (row & 7)) << 3)];
            }
#pragma unroll
            for (int m = 0; m < 4; ++m)
#pragma unroll
                for (int n = 0; n < 6; ++n)
                    acc[m][n] = __builtin_amdgcn_mfma_f32_16x16x32_bf16(af[m], bfr[n], acc[m][n], 0, 0, 0);
        }
        __syncthreads();
    }

    // per-lane channel constants
    float bt[6], gm[6], bta[6];
#pragma unroll
    for (int n = 0; n < 6; ++n) {
        int c = wcol * 96 + n * 16 + (lane & 15);
        bt[n]  = btot[b * C1D + c];
        gm[n]  = gamma[c];
        bta[n] = beta[c];
    }
    // row partial sums over this wave's 96 columns
    float sm[4][4], sq[4][4];
#pragma unroll
    for (int m = 0; m < 4; ++m)
#pragma unroll
        for (int r = 0; r < 4; ++r) { sm[m][r] = 0.f; sq[m][r] = 0.f; }
#pragma unroll
    for (int m = 0; m < 4; ++m)
#pragma unroll
        for (int n = 0; n < 6; ++n)
#pragma unroll
            for (int r = 0; r < 4; ++r) {
                float v = acc[m][n][r] + bt[n];
                sm[m][r] += v; sq[m][r] += v * v;
            }
#pragma unroll
    for (int off = 1; off < 16; off <<= 1)
#pragma unroll
        for (int m = 0; m < 4; ++m)
#pragma unroll
            for (int r = 0; r < 4; ++r) {
                sm[m][r] += __shfl_xor(sm[m][r], off, 64);
                sq[m][r] += __shfl_xor(sq[m][r], off, 64);
            }
    if ((lane & 15) == 0) {
#pragma unroll
        for (int m = 0; m < 4; ++m)
#pragma unroll
            for (int r = 0; r < 4; ++r) {
                int rl = wrow * 64 + m * 16 + (lane >> 4) * 4 + r;
                stats[rl * 8 + wcol * 2 + 0] = sm[m][r];
                stats[rl * 8 + wcol * 2 + 1] = sq[m][r];
            }
    }
    __syncthreads();
    float mu[4][4], rs[4][4];
#pragma unroll
    for (int m = 0; m < 4; ++m)
#pragma unroll
        for (int r = 0; r < 4; ++r) {
            int rl = wrow * 64 + m * 16 + (lane >> 4) * 4 + r;
            float s = 0.f, s2 = 0.f;
#pragma unroll
            for (int wc = 0; wc < 4; ++wc) {
                s  += stats[rl * 8 + wc * 2 + 0];
                s2 += stats[rl * 8 + wc * 2 + 1];
            }
            float m_ = s / C1D;
            mu[m][r] = m_;
            rs[m][r] = rsqrtf(s2 / C1D - m_ * m_ + LN_EPS);
        }

    float* Yb = Y + (size_t)b * C1D * LDIM;
    for (int ch = 0; ch < 4; ++ch) {
        if (wcol == ch) {
#pragma unroll
            for (int m = 0; m < 4; ++m)
#pragma unroll
                for (int n = 0; n < 6; ++n)
#pragma unroll
                    for (int r = 0; r < 4; ++r) {
                        int cl = n * 16 + (lane & 15);
                        int ll = wrow * 64 + m * 16 + (lane >> 4) * 4 + r;
                        float v = (acc[m][n][r] + bt[n] - mu[m][r]) * rs[m][r] * gm[n] + bta[n];
                        T[cl * 132 + ll] = v;
                    }
        }
        __syncthreads();
        for (int idx = t; idx < 96 * 128; idx += 512) {
            int cl = idx >> 7, ll = idx & 127;
            Yb[(size_t)(ch * 96 + cl) * LDIM + l0 + ll] = T[cl * 132 + ll];
        }
        __syncthreads();
    }
}

extern "C" void kernel_launch(void* const* d_in, const int* in_sizes, int n_in,
                              void* d_out, int out_size, void* d_ws, size_t ws_size,
                              hipStream_t stream) {
    const float* x1    = (const float*)d_in[0];
    const float* x2    = (const float*)d_in[1];
    const float* Wq    = (const float*)d_in[2];
    const float* bq    = (const float*)d_in[3];
    const float* Wk    = (const float*)d_in[4];
    const float* bk    = (const float*)d_in[5];
    const float* Wv    = (const float*)d_in[6];
    const float* bv    = (const float*)d_in[7];
    const float* Wo    = (const float*)d_in[8];
    const float* bo    = (const float*)d_in[9];
    const float* gamma = (const float*)d_in[10];
    const float* beta  = (const float*)d_in[11];
    float* out = (float*)d_out;

    char* p = (char*)d_ws;
    const size_t NB  = (size_t)BB * LDIM * ADIM;
    const size_t PBS = (size_t)LDIM * ADIM;    // per-batch stride
    unsigned short* X1p = (unsigned short*)p; p += NB * 2;
    unsigned short* X2p = (unsigned short*)p; p += NB;       // B*192*4096 elems = NB/2
    unsigned short* Kt  = (unsigned short*)p; p += NB * 2;
    unsigned short* Vt  = (unsigned short*)p; p += NB * 2;
    unsigned short* Wkp = (unsigned short*)p; p += (size_t)C2D * ADIM * 2;
    unsigned short* Wvp = (unsigned short*)p; p += (size_t)C2D * ADIM * 2;
    unsigned short* WoTp= (unsigned short*)p; p += (size_t)C1D * ADIM * 2;
    float* kvpart = (float*)p; p += (size_t)BB * NH * KVLC * KVP_STRIDE * 4;
    float* KVf    = (float*)p; p += (size_t)BB * NH * DHD * DHD * 4;
    unsigned short* Mbuf = (unsigned short*)p; p += (size_t)BB * C1D * ADIM * 2;
    unsigned short* WresT = (unsigned short*)p; p += (size_t)BB * C1D * C1D * 2;
    float* btot   = (float*)p; p += (size_t)BB * C1D * 4;

    float inv_scale = powf((float)DHD, -0.25f);

    transpose_cvt<<<dim3(LDIM / 32, C1D / 32, BB), 256, 0, stream>>>(x1, X1p, C1D, LDIM);
    transpose_cvt<<<dim3(LDIM / 32, C2D / 32, BB), 256, 0, stream>>>(x2, X2p, C2D, LDIM);
    transpose_cvt<<<dim3(ADIM / 32, C2D / 32, 1), 256, 0, stream>>>(Wk, Wkp, C2D, ADIM);
    transpose_cvt<<<dim3(ADIM / 32, C2D / 32, 1), 256, 0, stream>>>(Wv, Wvp, C2D, ADIM);
    transpose_cvt<<<dim3(C1D / 32, ADIM / 32, 1), 256, 0, stream>>>(Wo, WoTp, ADIM, C1D);

    // Kt[b,a,l], Vt[b,a,l]
    gemm_mfma<C2D, 2><<<dim3(ADIM / 128, LDIM / 128, BB), 256, 0, stream>>>(
        Wkp, 0, X2p, (size_t)LDIM * C2D, bk, Kt, PBS, LDIM, inv_scale);
    gemm_mfma<C2D, 2><<<dim3(ADIM / 128, LDIM / 128, BB), 256, 0, stream>>>(
        Wvp, 0, X2p, (size_t)LDIM * C2D, bv, Vt, PBS, LDIM, 1.0f);

    kv_part<<<dim3(KVLC, NH, BB), 64, 0, stream>>>(Kt, Vt, kvpart);
    kv_finalize<<<BB * NH, 256, 0, stream>>>(kvpart, KVf);

    m_kernel<<<dim3(C1D / 64, NH, BB), 256, 0, stream>>>(Wq, KVf, Mbuf, inv_scale);
    // W_resT[b][c'][c] = sum_a WoT[c'][a] * M[b][c][a] + (c'==c)   (MFMA)
    gemm_mfma<ADIM, 3><<<dim3(C1D / 128, C1D / 128, BB), 256, 0, stream>>>(
        WoTp, 0, Mbuf, (size_t)C1D * ADIM, bo /*unused*/, WresT, (size_t)C1D * C1D, C1D, 1.0f);
    btot_kernel<<<dim3(C1D / 32, BB), 256, 0, stream>>>(bq, KVf, Wo, bo, btot, inv_scale);

    // fused final GEMM + residual-bias + LayerNorm + transposed store
    gemm_ln<<<dim3(LDIM / 128, 1, BB), 512, 0, stream>>>(X1p, WresT, btot, gamma, beta, out);
}

// Round 10
// 133.851 us; speedup vs baseline: 1.8858x; 1.0664x over previous
//
#include <hip/hip_runtime.h>
#include <hip/hip_bf16.h>
#include <math.h>

#define BB 8
#define C1D 384
#define C2D 192
#define LDIM 4096
#define ADIM 384
#define NH 8
#define DHD 48
#define KVLC 16
#define KVP_STRIDE 2352   // 48*48 partials + 48 expsums
#define LN_EPS 1e-5f

typedef short s8v __attribute__((ext_vector_type(8)));
typedef float f4v __attribute__((ext_vector_type(4)));

__device__ __forceinline__ unsigned short f2bf(float f) {
    unsigned u = __builtin_bit_cast(unsigned, f);
    unsigned r = (u + 0x7FFFu + ((u >> 16) & 1u)) >> 16;
    return (unsigned short)r;
}
__device__ __forceinline__ float bf2f(unsigned short h) {
    unsigned u = ((unsigned)h) << 16;
    return __builtin_bit_cast(float, u);
}
__device__ __forceinline__ void gload16(const void* g, void* l) {
    __builtin_amdgcn_global_load_lds((const __attribute__((address_space(1))) void*)g,
                                     (__attribute__((address_space(3))) void*)l, 16, 0, 0);
}

// ---------- transpose fp32 [bz][R][Cols] -> bf16 [bz][Cols][R] ----------
__global__ __launch_bounds__(256) void transpose_cvt(const float* __restrict__ in,
                                                     unsigned short* __restrict__ out,
                                                     int R, int Cols)
{
    __shared__ float T[32][33];
    int b = blockIdx.z;
    int c0 = blockIdx.x * 32, r0 = blockIdx.y * 32;
    const float* ib = in + (size_t)b * R * Cols;
    unsigned short* ob = out + (size_t)b * R * Cols;
    int t = threadIdx.x;
#pragma unroll
    for (int i = 0; i < 4; ++i) {
        int idx = t + i * 256;
        int rr = idx >> 5, cc = idx & 31;
        T[rr][cc] = ib[(size_t)(r0 + rr) * Cols + c0 + cc];
    }
    __syncthreads();
#pragma unroll
    for (int i = 0; i < 2; ++i) {
        int idx = t + i * 256;
        int cc = idx >> 4, rp = (idx & 15) * 2;
        unsigned val = (unsigned)f2bf(T[rp][cc]) | ((unsigned)f2bf(T[rp + 1][cc]) << 16);
        *(unsigned*)&ob[(size_t)(c0 + cc) * R + r0 + rp] = val;
    }
}

// ---------- bf16 MFMA GEMM: Out[b,m,n] = scl_eff*(sum_k A[b,m,k]*Bt[b,n,k] + bias) ----------
// BMODE: 0 = no bias, 1 = bias over n, 2 = bias over m, 3 = add identity (row==col)
// scl_eff = (row < msplit) ? scl : scl2
template<int KD, int BMODE>
__global__ __launch_bounds__(256) void gemm_mfma(
    const unsigned short* __restrict__ A, size_t Abs,
    const unsigned short* __restrict__ Bt, size_t Bbs,
    const float* __restrict__ bias,
    unsigned short* __restrict__ Out, size_t Obs, int Ncols,
    float scl, float scl2, int msplit)
{
    __shared__ unsigned short As[128 * 64];
    __shared__ unsigned short Bs[128 * 64];
    const int t = threadIdx.x;
    const int lane = t & 63;
    const int w = t >> 6;
    const int wm = w >> 1, wn = w & 1;
    const int b = blockIdx.z;
    const int m0 = blockIdx.x * 128;
    const int n0 = blockIdx.y * 128;
    const float sEff = (m0 < msplit) ? scl : scl2;

    const unsigned short* Ab = A + Abs * b + (size_t)m0 * KD;
    const unsigned short* Bb = Bt + Bbs * b + (size_t)n0 * KD;

    f4v acc[4][4];
#pragma unroll
    for (int i = 0; i < 4; ++i)
#pragma unroll
        for (int j = 0; j < 4; ++j) acc[i][j] = (f4v)0.f;

    const int r_l = lane >> 3;
    const int q = lane & 7;

    for (int ks = 0; ks < KD; ks += 64) {
#pragma unroll
        for (int c = 0; c < 4; ++c) {
            int row = w * 32 + c * 8 + r_l;
            int koff = ((q ^ (row & 7)) << 3);
            gload16(Ab + (size_t)row * KD + ks + koff, &As[(w * 32 + c * 8) * 64]);
            gload16(Bb + (size_t)row * KD + ks + koff, &Bs[(w * 32 + c * 8) * 64]);
        }
        __syncthreads();
#pragma unroll
        for (int kh = 0; kh < 2; ++kh) {
            s8v af[4], bfr[4];
            int kq = kh * 4 + (lane >> 4);
#pragma unroll
            for (int m = 0; m < 4; ++m) {
                int row = wm * 64 + m * 16 + (lane & 15);
                af[m] = *(const s8v*)&As[row * 64 + ((kq ^ (row & 7)) << 3)];
            }
#pragma unroll
            for (int n = 0; n < 4; ++n) {
                int row = wn * 64 + n * 16 + (lane & 15);
                bfr[n] = *(const s8v*)&Bs[row * 64 + ((kq ^ (row & 7)) << 3)];
            }
#pragma unroll
            for (int m = 0; m < 4; ++m)
#pragma unroll
                for (int n = 0; n < 4; ++n)
                    acc[m][n] = __builtin_amdgcn_mfma_f32_16x16x32_bf16(af[m], bfr[n], acc[m][n], 0, 0, 0);
        }
        __syncthreads();
    }

    float bn[4], bm[4][4];
    if (BMODE == 2) {
#pragma unroll
        for (int m = 0; m < 4; ++m)
#pragma unroll
            for (int r = 0; r < 4; ++r)
                bm[m][r] = bias[m0 + wm * 64 + m * 16 + (lane >> 4) * 4 + r];
    } else if (BMODE == 1) {
#pragma unroll
        for (int n = 0; n < 4; ++n) bn[n] = bias[n0 + wn * 64 + n * 16 + (lane & 15)];
    }
#pragma unroll
    for (int m = 0; m < 4; ++m)
#pragma unroll
        for (int n = 0; n < 4; ++n) {
            int col = n0 + wn * 64 + n * 16 + (lane & 15);
#pragma unroll
            for (int r = 0; r < 4; ++r) {
                int row = m0 + wm * 64 + m * 16 + (lane >> 4) * 4 + r;
                float bb = (BMODE == 2) ? bm[m][r] : (BMODE == 1) ? bn[n] : 0.f;
                float v = (acc[m][n][r] + bb) * sEff;
                if (BMODE == 3 && row == col) v += 1.f;
                Out[Obs * b + (size_t)row * Ncols + col] = f2bf(v);
            }
        }
}

// ---------- kvpart from KVt [b][768][L] (rows 0-383 = K, 384-767 = V) ----------
__global__ __launch_bounds__(64) void kv_part(const unsigned short* __restrict__ KVt,
                                              float* __restrict__ kvpart)
{
    int lane = threadIdx.x;
    int b = blockIdx.z, h = blockIdx.y, lc = blockIdx.x;
    size_t base = ((size_t)b * 768 + h * DHD) * LDIM;
    const unsigned short* Kb = KVt + base;
    const unsigned short* Vb = Kb + (size_t)ADIM * LDIM;
    int lbase = lc * (LDIM / KVLC);

    f4v acc[3][3];
#pragma unroll
    for (int i = 0; i < 3; ++i)
#pragma unroll
        for (int j = 0; j < 3; ++j) acc[i][j] = (f4v)0.f;
    float es[3] = {0.f, 0.f, 0.f};

    for (int ks = 0; ks < LDIM / KVLC; ks += 32) {
        int l0 = lbase + ks + ((lane >> 4) * 8);
        s8v af[3], bfr[3];
#pragma unroll
        for (int me = 0; me < 3; ++me)
            af[me] = *(const s8v*)&Vb[(size_t)(me * 16 + (lane & 15)) * LDIM + l0];
#pragma unroll
        for (int nd = 0; nd < 3; ++nd) {
            s8v raw = *(const s8v*)&Kb[(size_t)(nd * 16 + (lane & 15)) * LDIM + l0];
#pragma unroll
            for (int j = 0; j < 8; ++j) {
                float e = __expf(bf2f((unsigned short)raw[j]));
                es[nd] += e;
                bfr[nd][j] = (short)f2bf(e);
            }
        }
#pragma unroll
        for (int me = 0; me < 3; ++me)
#pragma unroll
            for (int nd = 0; nd < 3; ++nd)
                acc[me][nd] = __builtin_amdgcn_mfma_f32_16x16x32_bf16(af[me], bfr[nd], acc[me][nd], 0, 0, 0);
    }
    float* pp = kvpart + (((size_t)(b * NH + h) * KVLC) + lc) * KVP_STRIDE;
#pragma unroll
    for (int me = 0; me < 3; ++me)
#pragma unroll
        for (int nd = 0; nd < 3; ++nd)
#pragma unroll
            for (int r = 0; r < 4; ++r) {
                int e = me * 16 + (lane >> 4) * 4 + r;   // C/D row
                int d = nd * 16 + (lane & 15);           // C/D col
                pp[e * DHD + d] = acc[me][nd][r];
            }
#pragma unroll
    for (int nd = 0; nd < 3; ++nd) {
        float s = es[nd];
        s += __shfl_xor(s, 16, 64);
        s += __shfl_xor(s, 32, 64);
        if (lane < 16) pp[2304 + nd * 16 + lane] = s;
    }
}

// ---------- KVf[bh][d*48+e] = (sum_lc part[e][d]) / (sum_lc expsum[d]) ----------
__global__ __launch_bounds__(256) void kv_finalize(const float* __restrict__ kvpart,
                                                   float* __restrict__ KVf)
{
    __shared__ float isl_s[DHD];
    int bh = blockIdx.x, t = threadIdx.x;
    const float* pp = kvpart + (size_t)bh * KVLC * KVP_STRIDE;
    if (t < DHD) {
        float s = 0.f;
#pragma unroll
        for (int lc = 0; lc < KVLC; ++lc) s += pp[lc * KVP_STRIDE + 2304 + t];
        isl_s[t] = 1.f / s;
    }
    __syncthreads();
    for (int idx = t; idx < DHD * DHD; idx += 256) {
        int d = idx / DHD, e = idx % DHD;
        float s = 0.f;
#pragma unroll
        for (int lc = 0; lc < KVLC; ++lc) s += pp[lc * KVP_STRIDE + e * DHD + d];
        KVf[(size_t)bh * DHD * DHD + idx] = s * isl_s[d];
    }
}

// ---------- M[b][c][he] bf16 = sum_d Wq[c][hd] * KVf[bh][d][e] * inv_scale ----------
__global__ __launch_bounds__(256) void m_kernel(const float* __restrict__ Wq,
                                                const float* __restrict__ KVf,
                                                unsigned short* __restrict__ M, float inv_scale)
{
    __shared__ float kvs[DHD * DHD];
    int c0 = blockIdx.x * 64, h = blockIdx.y, b = blockIdx.z;
    int t = threadIdx.x;
    for (int idx = t; idx < DHD * DHD; idx += 256)
        kvs[idx] = KVf[((size_t)(b * NH + h)) * DHD * DHD + idx];
    __syncthreads();
    int cl = t >> 2, qq = t & 3;   // 64 rows x 4 column-quarters
    int c = c0 + cl;
    float wq[DHD];
#pragma unroll
    for (int d = 0; d < DHD; ++d) wq[d] = Wq[(size_t)c * ADIM + h * DHD + d];
    float s[12];
#pragma unroll
    for (int j = 0; j < 12; ++j) s[j] = 0.f;
#pragma unroll
    for (int d = 0; d < DHD; ++d) {
        float w = wq[d];
#pragma unroll
        for (int j = 0; j < 12; ++j)
            s[j] += w * kvs[d * DHD + qq * 12 + j];
    }
#pragma unroll
    for (int j = 0; j < 12; ++j)
        M[((size_t)b * C1D + c) * ADIM + h * DHD + qq * 12 + j] = f2bf(s[j] * inv_scale);
}

// ---------- btot[b][c'] = sum_he c0s[he]*Wo[he][c'] + bo[c'] (parallel) ----------
__global__ __launch_bounds__(256) void btot_kernel(const float* __restrict__ bq,
                                                   const float* __restrict__ KVf,
                                                   const float* __restrict__ Wo,
                                                   const float* __restrict__ bo,
                                                   float* __restrict__ btot, float inv_scale)
{
    __shared__ float c0s[ADIM];
    int cp0 = blockIdx.x * 32, b = blockIdx.y, t = threadIdx.x;
    for (int idx = t; idx < ADIM; idx += 256) {
        int h = idx / DHD, e = idx % DHD;
        float s = 0.f;
#pragma unroll
        for (int d = 0; d < DHD; ++d)
            s += bq[h * DHD + d] * KVf[((size_t)(b * NH + h)) * DHD * DHD + d * DHD + e];
        c0s[idx] = s * inv_scale;
    }
    __syncthreads();
    int cp = cp0 + (t >> 3), part = t & 7;
    float s = 0.f;
#pragma unroll
    for (int i = 0; i < 48; ++i) {
        int he = part * 48 + i;
        s += c0s[he] * Wo[(size_t)he * C1D + cp];
    }
    s += __shfl_xor(s, 1, 64);
    s += __shfl_xor(s, 2, 64);
    s += __shfl_xor(s, 4, 64);
    if (part == 0) btot[b * C1D + cp] = s + bo[cp];
}

// ---------- fused: OUT[l][c] = x1f . W_res (x1 cvt+transpose inline); +btot; LN; store Y[b][c][l] ----------
__global__ __launch_bounds__(512) void gemm_ln(
    const float* __restrict__ x1,             // [b][384][4096] fp32
    const unsigned short* __restrict__ Bt,    // WresT [b][384][384]
    const float* __restrict__ btot,
    const float* __restrict__ gamma,
    const float* __restrict__ beta,
    float* __restrict__ Y)                    // [b][384][4096]
{
    __shared__ __align__(16) char lds[65536];
    unsigned short* As = (unsigned short*)lds;                 // [128][64] bf16
    unsigned short* Bs = (unsigned short*)(lds + 16384);       // [384][64] bf16
    float* stats = (float*)lds;                                // [128][4][2] (after K-loop)
    float* T = (float*)(lds + 8192);                           // [96][132]

    const int t = threadIdx.x;
    const int lane = t & 63;
    const int w = t >> 6;           // 0..7
    const int wrow = w >> 2, wcol = w & 3;
    const int b = blockIdx.z;
    const int l0 = blockIdx.x * 128;

    const float* x1b = x1 + (size_t)b * C1D * LDIM + l0;
    const unsigned short* Bb = Bt + (size_t)b * C1D * C1D;

    f4v acc[4][6];
#pragma unroll
    for (int m = 0; m < 4; ++m)
#pragma unroll
        for (int n = 0; n < 6; ++n) acc[m][n] = (f4v)0.f;

    const int r_l = lane >> 3;
    const int q = lane & 7;

    for (int ks = 0; ks < C1D; ks += 64) {
        // A-tile: gather-transpose-cvt from x1 [c][l] -> As[l][64c] (XOR-swizzled)
#pragma unroll
        for (int i = 0; i < 2; ++i) {
            int item = t + i * 512;          // 1024 = 128 l x 8 c-groups
            int l = item & 127;
            int c8 = item >> 7;
            const float* src = x1b + (size_t)(ks + c8 * 8) * LDIM + l;
            unsigned short tmp[8];
#pragma unroll
            for (int c = 0; c < 8; ++c) tmp[c] = f2bf(src[(size_t)c * LDIM]);
            *(s8v*)&As[l * 64 + ((c8 ^ (l & 7)) << 3)] = *(const s8v*)tmp;
        }
        // B-tile: WresT via global_load_lds
#pragma unroll
        for (int c = 0; c < 6; ++c) {
            int row = w * 48 + c * 8 + r_l;
            int koff = ((q ^ (row & 7)) << 3);
            gload16(Bb + (size_t)row * C1D + ks + koff, &Bs[(w * 48 + c * 8) * 64]);
        }
        __syncthreads();
#pragma unroll
        for (int kh = 0; kh < 2; ++kh) {
            int kq = kh * 4 + (lane >> 4);
            s8v af[4], bfr[6];
#pragma unroll
            for (int m = 0; m < 4; ++m) {
                int row = wrow * 64 + m * 16 + (lane & 15);
                af[m] = *(const s8v*)&As[row * 64 + ((kq ^ (row & 7)) << 3)];
            }
#pragma unroll
            for (int n = 0; n < 6; ++n) {
                int row = wcol * 96 + n * 16 + (lane & 15);
                bfr[n] = *(const s8v*)&Bs[row * 64 + ((kq ^ (row & 7)) << 3)];
            }
#pragma unroll
            for (int m = 0; m < 4; ++m)
#pragma unroll
                for (int n = 0; n < 6; ++n)
                    acc[m][n] = __builtin_amdgcn_mfma_f32_16x16x32_bf16(af[m], bfr[n], acc[m][n], 0, 0, 0);
        }
        __syncthreads();
    }

    // per-lane channel constants
    float bt[6], gm[6], bta[6];
#pragma unroll
    for (int n = 0; n < 6; ++n) {
        int c = wcol * 96 + n * 16 + (lane & 15);
        bt[n]  = btot[b * C1D + c];
        gm[n]  = gamma[c];
        bta[n] = beta[c];
    }
    // row partial sums over this wave's 96 columns
    float sm[4][4], sq[4][4];
#pragma unroll
    for (int m = 0; m < 4; ++m)
#pragma unroll
        for (int r = 0; r < 4; ++r) { sm[m][r] = 0.f; sq[m][r] = 0.f; }
#pragma unroll
    for (int m = 0; m < 4; ++m)
#pragma unroll
        for (int n = 0; n < 6; ++n)
#pragma unroll
            for (int r = 0; r < 4; ++r) {
                float v = acc[m][n][r] + bt[n];
                sm[m][r] += v; sq[m][r] += v * v;
            }
#pragma unroll
    for (int off = 1; off < 16; off <<= 1)
#pragma unroll
        for (int m = 0; m < 4; ++m)
#pragma unroll
            for (int r = 0; r < 4; ++r) {
                sm[m][r] += __shfl_xor(sm[m][r], off, 64);
                sq[m][r] += __shfl_xor(sq[m][r], off, 64);
            }
    if ((lane & 15) == 0) {
#pragma unroll
        for (int m = 0; m < 4; ++m)
#pragma unroll
            for (int r = 0; r < 4; ++r) {
                int rl = wrow * 64 + m * 16 + (lane >> 4) * 4 + r;
                stats[rl * 8 + wcol * 2 + 0] = sm[m][r];
                stats[rl * 8 + wcol * 2 + 1] = sq[m][r];
            }
    }
    __syncthreads();
    float mu[4][4], rs[4][4];
#pragma unroll
    for (int m = 0; m < 4; ++m)
#pragma unroll
        for (int r = 0; r < 4; ++r) {
            int rl = wrow * 64 + m * 16 + (lane >> 4) * 4 + r;
            float s = 0.f, s2 = 0.f;
#pragma unroll
            for (int wc = 0; wc < 4; ++wc) {
                s  += stats[rl * 8 + wc * 2 + 0];
                s2 += stats[rl * 8 + wc * 2 + 1];
            }
            float m_ = s / C1D;
            mu[m][r] = m_;
            rs[m][r] = rsqrtf(s2 / C1D - m_ * m_ + LN_EPS);
        }

    float* Yb = Y + (size_t)b * C1D * LDIM;
    for (int ch = 0; ch < 4; ++ch) {
        if (wcol == ch) {
#pragma unroll
            for (int m = 0; m < 4; ++m)
#pragma unroll
                for (int n = 0; n < 6; ++n)
#pragma unroll
                    for (int r = 0; r < 4; ++r) {
                        int cl = n * 16 + (lane & 15);
                        int ll = wrow * 64 + m * 16 + (lane >> 4) * 4 + r;
                        float v = (acc[m][n][r] + bt[n] - mu[m][r]) * rs[m][r] * gm[n] + bta[n];
                        T[cl * 132 + ll] = v;
                    }
        }
        __syncthreads();
        for (int idx = t; idx < 96 * 128; idx += 512) {
            int cl = idx >> 7, ll = idx & 127;
            Yb[(size_t)(ch * 96 + cl) * LDIM + l0 + ll] = T[cl * 132 + ll];
        }
        __syncthreads();
    }
}

extern "C" void kernel_launch(void* const* d_in, const int* in_sizes, int n_in,
                              void* d_out, int out_size, void* d_ws, size_t ws_size,
                              hipStream_t stream) {
    const float* x1    = (const float*)d_in[0];
    const float* x2    = (const float*)d_in[1];
    const float* Wq    = (const float*)d_in[2];
    const float* bq    = (const float*)d_in[3];
    const float* Wk    = (const float*)d_in[4];
    const float* bk    = (const float*)d_in[5];
    const float* Wv    = (const float*)d_in[6];
    const float* bv    = (const float*)d_in[7];
    const float* Wo    = (const float*)d_in[8];
    const float* bo    = (const float*)d_in[9];
    const float* gamma = (const float*)d_in[10];
    const float* beta  = (const float*)d_in[11];
    float* out = (float*)d_out;

    char* p = (char*)d_ws;
    const size_t NB  = (size_t)BB * LDIM * ADIM;
    unsigned short* X2p = (unsigned short*)p; p += NB;       // B*192*4096 bf16
    unsigned short* KVt = (unsigned short*)p; p += (size_t)BB * 768 * LDIM * 2;  // K rows 0-383, V rows 384-767
    unsigned short* Wkvp= (unsigned short*)p; p += (size_t)768 * C2D * 2;        // Wk pack then Wv pack (adjacent)
    unsigned short* WoTp= (unsigned short*)p; p += (size_t)C1D * ADIM * 2;
    float* bkv    = (float*)p; p += 768 * 4;
    float* kvpart = (float*)p; p += (size_t)BB * NH * KVLC * KVP_STRIDE * 4;
    float* KVf    = (float*)p; p += (size_t)BB * NH * DHD * DHD * 4;
    unsigned short* Mbuf = (unsigned short*)p; p += (size_t)BB * C1D * ADIM * 2;
    unsigned short* WresT = (unsigned short*)p; p += (size_t)BB * C1D * C1D * 2;
    float* btot   = (float*)p; p += (size_t)BB * C1D * 4;

    float inv_scale = powf((float)DHD, -0.25f);

    transpose_cvt<<<dim3(LDIM / 32, C2D / 32, BB), 256, 0, stream>>>(x2, X2p, C2D, LDIM);
    transpose_cvt<<<dim3(ADIM / 32, C2D / 32, 1), 256, 0, stream>>>(Wk, Wkvp, C2D, ADIM);
    transpose_cvt<<<dim3(ADIM / 32, C2D / 32, 1), 256, 0, stream>>>(Wv, Wkvp + (size_t)ADIM * C2D, C2D, ADIM);
    transpose_cvt<<<dim3(C1D / 32, ADIM / 32, 1), 256, 0, stream>>>(Wo, WoTp, ADIM, C1D);
    hipMemcpyAsync(bkv,       bk, ADIM * sizeof(float), hipMemcpyDeviceToDevice, stream);
    hipMemcpyAsync(bkv + ADIM, bv, ADIM * sizeof(float), hipMemcpyDeviceToDevice, stream);

    // KVt[b, 0:384, l] = K (scaled), KVt[b, 384:768, l] = V
    gemm_mfma<C2D, 2><<<dim3(768 / 128, LDIM / 128, BB), 256, 0, stream>>>(
        Wkvp, 0, X2p, (size_t)LDIM * C2D, bkv, KVt, (size_t)768 * LDIM, LDIM,
        inv_scale, 1.0f, ADIM);

    kv_part<<<dim3(KVLC, NH, BB), 64, 0, stream>>>(KVt, kvpart);
    kv_finalize<<<BB * NH, 256, 0, stream>>>(kvpart, KVf);

    m_kernel<<<dim3(C1D / 64, NH, BB), 256, 0, stream>>>(Wq, KVf, Mbuf, inv_scale);
    // W_resT[b][c'][c] = sum_a WoT[c'][a] * M[b][c][a] + (c'==c)   (MFMA)
    gemm_mfma<ADIM, 3><<<dim3(C1D / 128, C1D / 128, BB), 256, 0, stream>>>(
        WoTp, 0, Mbuf, (size_t)C1D * ADIM, bo /*unused*/, WresT, (size_t)C1D * C1D, C1D,
        1.0f, 1.0f, 1 << 30);
    btot_kernel<<<dim3(C1D / 32, BB), 256, 0, stream>>>(bq, KVf, Wo, bo, btot, inv_scale);

    // fused final GEMM (x1 transposed+cvt inline) + residual-bias + LayerNorm + transposed store
    gemm_ln<<<dim3(LDIM / 128, 1, BB), 512, 0, stream>>>(x1, WresT, btot, gamma, beta, out);
}

// Round 11
// 133.516 us; speedup vs baseline: 1.8905x; 1.0025x over previous
//
#include <hip/hip_runtime.h>
#include <hip/hip_bf16.h>
#include <math.h>

#define BB 8
#define C1D 384
#define C2D 192
#define LDIM 4096
#define ADIM 384
#define NH 8
#define DHD 48
#define KVLC 16
#define KVP_STRIDE 2352   // 48*48 partials + 48 expsums
#define LN_EPS 1e-5f

typedef short s8v __attribute__((ext_vector_type(8)));
typedef float f4v __attribute__((ext_vector_type(4)));

__device__ __forceinline__ unsigned short f2bf(float f) {
    unsigned u = __builtin_bit_cast(unsigned, f);
    unsigned r = (u + 0x7FFFu + ((u >> 16) & 1u)) >> 16;
    return (unsigned short)r;
}
__device__ __forceinline__ float bf2f(unsigned short h) {
    unsigned u = ((unsigned)h) << 16;
    return __builtin_bit_cast(float, u);
}
__device__ __forceinline__ void gload16(const void* g, void* l) {
    __builtin_amdgcn_global_load_lds((const __attribute__((address_space(1))) void*)g,
                                     (__attribute__((address_space(3))) void*)l, 16, 0, 0);
}

// ---------- transpose fp32 [bz][R][Cols] -> bf16 [bz][Cols][R] ----------
__global__ __launch_bounds__(256) void transpose_cvt(const float* __restrict__ in,
                                                     unsigned short* __restrict__ out,
                                                     int R, int Cols)
{
    __shared__ float T[32][33];
    int b = blockIdx.z;
    int c0 = blockIdx.x * 32, r0 = blockIdx.y * 32;
    const float* ib = in + (size_t)b * R * Cols;
    unsigned short* ob = out + (size_t)b * R * Cols;
    int t = threadIdx.x;
#pragma unroll
    for (int i = 0; i < 4; ++i) {
        int idx = t + i * 256;
        int rr = idx >> 5, cc = idx & 31;
        T[rr][cc] = ib[(size_t)(r0 + rr) * Cols + c0 + cc];
    }
    __syncthreads();
#pragma unroll
    for (int i = 0; i < 2; ++i) {
        int idx = t + i * 256;
        int cc = idx >> 4, rp = (idx & 15) * 2;
        unsigned val = (unsigned)f2bf(T[rp][cc]) | ((unsigned)f2bf(T[rp + 1][cc]) << 16);
        *(unsigned*)&ob[(size_t)(c0 + cc) * R + r0 + rp] = val;
    }
}

// ---------- bf16 MFMA GEMM: Out[b,m,n] = scl_eff*(sum_k A[b,m,k]*Bt[b,n,k] + bias) ----------
// BMODE: 0 = no bias, 1 = bias over n, 2 = bias over m, 3 = add identity (row==col)
template<int KD, int BMODE>
__global__ __launch_bounds__(256) void gemm_mfma(
    const unsigned short* __restrict__ A, size_t Abs,
    const unsigned short* __restrict__ Bt, size_t Bbs,
    const float* __restrict__ bias,
    unsigned short* __restrict__ Out, size_t Obs, int Ncols,
    float scl, float scl2, int msplit)
{
    __shared__ unsigned short As[128 * 64];
    __shared__ unsigned short Bs[128 * 64];
    const int t = threadIdx.x;
    const int lane = t & 63;
    const int w = t >> 6;
    const int wm = w >> 1, wn = w & 1;
    const int b = blockIdx.z;
    const int m0 = blockIdx.x * 128;
    const int n0 = blockIdx.y * 128;
    const float sEff = (m0 < msplit) ? scl : scl2;

    const unsigned short* Ab = A + Abs * b + (size_t)m0 * KD;
    const unsigned short* Bb = Bt + Bbs * b + (size_t)n0 * KD;

    f4v acc[4][4];
#pragma unroll
    for (int i = 0; i < 4; ++i)
#pragma unroll
        for (int j = 0; j < 4; ++j) acc[i][j] = (f4v)0.f;

    const int r_l = lane >> 3;
    const int q = lane & 7;

    for (int ks = 0; ks < KD; ks += 64) {
#pragma unroll
        for (int c = 0; c < 4; ++c) {
            int row = w * 32 + c * 8 + r_l;
            int koff = ((q ^ (row & 7)) << 3);
            gload16(Ab + (size_t)row * KD + ks + koff, &As[(w * 32 + c * 8) * 64]);
            gload16(Bb + (size_t)row * KD + ks + koff, &Bs[(w * 32 + c * 8) * 64]);
        }
        __syncthreads();
#pragma unroll
        for (int kh = 0; kh < 2; ++kh) {
            s8v af[4], bfr[4];
            int kq = kh * 4 + (lane >> 4);
#pragma unroll
            for (int m = 0; m < 4; ++m) {
                int row = wm * 64 + m * 16 + (lane & 15);
                af[m] = *(const s8v*)&As[row * 64 + ((kq ^ (row & 7)) << 3)];
            }
#pragma unroll
            for (int n = 0; n < 4; ++n) {
                int row = wn * 64 + n * 16 + (lane & 15);
                bfr[n] = *(const s8v*)&Bs[row * 64 + ((kq ^ (row & 7)) << 3)];
            }
#pragma unroll
            for (int m = 0; m < 4; ++m)
#pragma unroll
                for (int n = 0; n < 4; ++n)
                    acc[m][n] = __builtin_amdgcn_mfma_f32_16x16x32_bf16(af[m], bfr[n], acc[m][n], 0, 0, 0);
        }
        __syncthreads();
    }

    float bn[4], bm[4][4];
    if (BMODE == 2) {
#pragma unroll
        for (int m = 0; m < 4; ++m)
#pragma unroll
            for (int r = 0; r < 4; ++r)
                bm[m][r] = bias[m0 + wm * 64 + m * 16 + (lane >> 4) * 4 + r];
    } else if (BMODE == 1) {
#pragma unroll
        for (int n = 0; n < 4; ++n) bn[n] = bias[n0 + wn * 64 + n * 16 + (lane & 15)];
    }
#pragma unroll
    for (int m = 0; m < 4; ++m)
#pragma unroll
        for (int n = 0; n < 4; ++n) {
            int col = n0 + wn * 64 + n * 16 + (lane & 15);
#pragma unroll
            for (int r = 0; r < 4; ++r) {
                int row = m0 + wm * 64 + m * 16 + (lane >> 4) * 4 + r;
                float bb = (BMODE == 2) ? bm[m][r] : (BMODE == 1) ? bn[n] : 0.f;
                float v = (acc[m][n][r] + bb) * sEff;
                if (BMODE == 3 && row == col) v += 1.f;
                Out[Obs * b + (size_t)row * Ncols + col] = f2bf(v);
            }
        }
}

// ---------- kvpart from KVt [b][768][L] (rows 0-383 = K, 384-767 = V) ----------
__global__ __launch_bounds__(64) void kv_part(const unsigned short* __restrict__ KVt,
                                              float* __restrict__ kvpart)
{
    int lane = threadIdx.x;
    int b = blockIdx.z, h = blockIdx.y, lc = blockIdx.x;
    size_t base = ((size_t)b * 768 + h * DHD) * LDIM;
    const unsigned short* Kb = KVt + base;
    const unsigned short* Vb = Kb + (size_t)ADIM * LDIM;
    int lbase = lc * (LDIM / KVLC);

    f4v acc[3][3];
#pragma unroll
    for (int i = 0; i < 3; ++i)
#pragma unroll
        for (int j = 0; j < 3; ++j) acc[i][j] = (f4v)0.f;
    float es[3] = {0.f, 0.f, 0.f};

    for (int ks = 0; ks < LDIM / KVLC; ks += 32) {
        int l0 = lbase + ks + ((lane >> 4) * 8);
        s8v af[3], bfr[3];
#pragma unroll
        for (int me = 0; me < 3; ++me)
            af[me] = *(const s8v*)&Vb[(size_t)(me * 16 + (lane & 15)) * LDIM + l0];
#pragma unroll
        for (int nd = 0; nd < 3; ++nd) {
            s8v raw = *(const s8v*)&Kb[(size_t)(nd * 16 + (lane & 15)) * LDIM + l0];
#pragma unroll
            for (int j = 0; j < 8; ++j) {
                float e = __expf(bf2f((unsigned short)raw[j]));
                es[nd] += e;
                bfr[nd][j] = (short)f2bf(e);
            }
        }
#pragma unroll
        for (int me = 0; me < 3; ++me)
#pragma unroll
            for (int nd = 0; nd < 3; ++nd)
                acc[me][nd] = __builtin_amdgcn_mfma_f32_16x16x32_bf16(af[me], bfr[nd], acc[me][nd], 0, 0, 0);
    }
    float* pp = kvpart + (((size_t)(b * NH + h) * KVLC) + lc) * KVP_STRIDE;
#pragma unroll
    for (int me = 0; me < 3; ++me)
#pragma unroll
        for (int nd = 0; nd < 3; ++nd)
#pragma unroll
            for (int r = 0; r < 4; ++r) {
                int e = me * 16 + (lane >> 4) * 4 + r;   // C/D row
                int d = nd * 16 + (lane & 15);           // C/D col
                pp[e * DHD + d] = acc[me][nd][r];
            }
#pragma unroll
    for (int nd = 0; nd < 3; ++nd) {
        float s = es[nd];
        s += __shfl_xor(s, 16, 64);
        s += __shfl_xor(s, 32, 64);
        if (lane < 16) pp[2304 + nd * 16 + lane] = s;
    }
}

// ---------- KVf[bh][d*48+e] = (sum_lc part[e][d]) / (sum_lc expsum[d]) ----------
__global__ __launch_bounds__(256) void kv_finalize(const float* __restrict__ kvpart,
                                                   float* __restrict__ KVf)
{
    __shared__ float isl_s[DHD];
    int bh = blockIdx.x, t = threadIdx.x;
    const float* pp = kvpart + (size_t)bh * KVLC * KVP_STRIDE;
    if (t < DHD) {
        float s = 0.f;
#pragma unroll
        for (int lc = 0; lc < KVLC; ++lc) s += pp[lc * KVP_STRIDE + 2304 + t];
        isl_s[t] = 1.f / s;
    }
    __syncthreads();
    for (int idx = t; idx < DHD * DHD; idx += 256) {
        int d = idx / DHD, e = idx % DHD;
        float s = 0.f;
#pragma unroll
        for (int lc = 0; lc < KVLC; ++lc) s += pp[lc * KVP_STRIDE + e * DHD + d];
        KVf[(size_t)bh * DHD * DHD + idx] = s * isl_s[d];
    }
}

// ---------- M[b][c][he] bf16 = sum_d Wq[c][hd] * KVf[bh][d][e] * inv_scale ----------
__global__ __launch_bounds__(256) void m_kernel(const float* __restrict__ Wq,
                                                const float* __restrict__ KVf,
                                                unsigned short* __restrict__ M, float inv_scale)
{
    __shared__ float kvs[DHD * DHD];
    int c0 = blockIdx.x * 64, h = blockIdx.y, b = blockIdx.z;
    int t = threadIdx.x;
    for (int idx = t; idx < DHD * DHD; idx += 256)
        kvs[idx] = KVf[((size_t)(b * NH + h)) * DHD * DHD + idx];
    __syncthreads();
    int cl = t >> 2, qq = t & 3;   // 64 rows x 4 column-quarters
    int c = c0 + cl;
    float wq[DHD];
#pragma unroll
    for (int d = 0; d < DHD; ++d) wq[d] = Wq[(size_t)c * ADIM + h * DHD + d];
    float s[12];
#pragma unroll
    for (int j = 0; j < 12; ++j) s[j] = 0.f;
#pragma unroll
    for (int d = 0; d < DHD; ++d) {
        float w = wq[d];
#pragma unroll
        for (int j = 0; j < 12; ++j)
            s[j] += w * kvs[d * DHD + qq * 12 + j];
    }
#pragma unroll
    for (int j = 0; j < 12; ++j)
        M[((size_t)b * C1D + c) * ADIM + h * DHD + qq * 12 + j] = f2bf(s[j] * inv_scale);
}

// ---------- btot[b][c'] = sum_he c0s[he]*Wo[he][c'] + bo[c'] (parallel) ----------
__global__ __launch_bounds__(256) void btot_kernel(const float* __restrict__ bq,
                                                   const float* __restrict__ KVf,
                                                   const float* __restrict__ Wo,
                                                   const float* __restrict__ bo,
                                                   float* __restrict__ btot, float inv_scale)
{
    __shared__ float c0s[ADIM];
    int cp0 = blockIdx.x * 32, b = blockIdx.y, t = threadIdx.x;
    for (int idx = t; idx < ADIM; idx += 256) {
        int h = idx / DHD, e = idx % DHD;
        float s = 0.f;
#pragma unroll
        for (int d = 0; d < DHD; ++d)
            s += bq[h * DHD + d] * KVf[((size_t)(b * NH + h)) * DHD * DHD + d * DHD + e];
        c0s[idx] = s * inv_scale;
    }
    __syncthreads();
    int cp = cp0 + (t >> 3), part = t & 7;
    float s = 0.f;
#pragma unroll
    for (int i = 0; i < 48; ++i) {
        int he = part * 48 + i;
        s += c0s[he] * Wo[(size_t)he * C1D + cp];
    }
    s += __shfl_xor(s, 1, 64);
    s += __shfl_xor(s, 2, 64);
    s += __shfl_xor(s, 4, 64);
    if (part == 0) btot[b * C1D + cp] = s + bo[cp];
}

// ---------- fused: OUT[l][c] = x1f . W_res (x1 cvt+transpose inline, issue-early); +btot; LN; Y[b][c][l] ----------
// 64-row tile, 8 waves x (64 rows x 48 cols); grid 512 blocks = 2/CU
__global__ __launch_bounds__(512, 4) void gemm_ln(
    const float* __restrict__ x1,             // [b][384][4096] fp32
    const unsigned short* __restrict__ Bt,    // WresT [b][384][384]
    const float* __restrict__ btot,
    const float* __restrict__ gamma,
    const float* __restrict__ beta,
    float* __restrict__ Y)                    // [b][384][4096]
{
    __shared__ __align__(16) char lds[60416];
    unsigned short* As = (unsigned short*)lds;                 // [64][64] bf16   (8 KB)
    unsigned short* Bs = (unsigned short*)(lds + 8192);        // [384][64] bf16  (48 KB)
    float* stats = (float*)lds;                                // [64][8][2] f32 (alias, post K-loop)
    float* T = (float*)(lds + 8192);                           // [192][68] f32  (alias)

    const int t = threadIdx.x;
    const int lane = t & 63;
    const int w = t >> 6;           // 0..7; wave w owns cols [w*48, w*48+48)
    const int b = blockIdx.z;
    const int l0 = blockIdx.x * 64;

    const float* x1b = x1 + (size_t)b * C1D * LDIM + l0;
    const unsigned short* Bb = Bt + (size_t)b * C1D * C1D;

    f4v acc[4][3];
#pragma unroll
    for (int m = 0; m < 4; ++m)
#pragma unroll
        for (int n = 0; n < 3; ++n) acc[m][n] = (f4v)0.f;

    const int r_l = lane >> 3;
    const int q = lane & 7;
    const int al = t & 63;          // A-gather: row within tile
    const int ac8 = t >> 6;         // A-gather: c-octet 0..7

    float a_reg[8];
#pragma unroll
    for (int c = 0; c < 8; ++c)
        a_reg[c] = x1b[(size_t)(ac8 * 8 + c) * LDIM + al];

    for (int ks6 = 0; ks6 < 6; ++ks6) {
        int ks = ks6 * 64;
        // write staged A regs -> LDS (swizzled), stage B via global_load_lds
        {
            unsigned short tmp[8];
#pragma unroll
            for (int c = 0; c < 8; ++c) tmp[c] = f2bf(a_reg[c]);
            *(s8v*)&As[al * 64 + ((ac8 ^ (al & 7)) << 3)] = *(const s8v*)tmp;
        }
#pragma unroll
        for (int c = 0; c < 6; ++c) {
            int row = w * 48 + c * 8 + r_l;
            int koff = ((q ^ (row & 7)) << 3);
            gload16(Bb + (size_t)row * C1D + ks + koff, &Bs[(w * 48 + c * 8) * 64]);
        }
        __syncthreads();
        // issue-early: next K-step's A loads fly during MFMA
        if (ks6 < 5) {
#pragma unroll
            for (int c = 0; c < 8; ++c)
                a_reg[c] = x1b[(size_t)(ks + 64 + ac8 * 8 + c) * LDIM + al];
        }
#pragma unroll
        for (int kh = 0; kh < 2; ++kh) {
            int kq = kh * 4 + (lane >> 4);
            s8v af[4], bfr[3];
#pragma unroll
            for (int m = 0; m < 4; ++m) {
                int row = m * 16 + (lane & 15);
                af[m] = *(const s8v*)&As[row * 64 + ((kq ^ (row & 7)) << 3)];
            }
#pragma unroll
            for (int n = 0; n < 3; ++n) {
                int row = w * 48 + n * 16 + (lane & 15);
                bfr[n] = *(const s8v*)&Bs[row * 64 + ((kq ^ (row & 7)) << 3)];
            }
#pragma unroll
            for (int m = 0; m < 4; ++m)
#pragma unroll
                for (int n = 0; n < 3; ++n)
                    acc[m][n] = __builtin_amdgcn_mfma_f32_16x16x32_bf16(af[m], bfr[n], acc[m][n], 0, 0, 0);
        }
        __syncthreads();
    }

    // per-lane channel constants
    float bt[3], gm[3], bta[3];
#pragma unroll
    for (int n = 0; n < 3; ++n) {
        int c = w * 48 + n * 16 + (lane & 15);
        bt[n]  = btot[b * C1D + c];
        gm[n]  = gamma[c];
        bta[n] = beta[c];
    }
    // row partials over this wave's 48 columns
    float sm[4][4], sq[4][4];
#pragma unroll
    for (int m = 0; m < 4; ++m)
#pragma unroll
        for (int r = 0; r < 4; ++r) { sm[m][r] = 0.f; sq[m][r] = 0.f; }
#pragma unroll
    for (int m = 0; m < 4; ++m)
#pragma unroll
        for (int n = 0; n < 3; ++n)
#pragma unroll
            for (int r = 0; r < 4; ++r) {
                float v = acc[m][n][r] + bt[n];
                sm[m][r] += v; sq[m][r] += v * v;
            }
#pragma unroll
    for (int off = 1; off < 16; off <<= 1)
#pragma unroll
        for (int m = 0; m < 4; ++m)
#pragma unroll
            for (int r = 0; r < 4; ++r) {
                sm[m][r] += __shfl_xor(sm[m][r], off, 64);
                sq[m][r] += __shfl_xor(sq[m][r], off, 64);
            }
    if ((lane & 15) == 0) {
#pragma unroll
        for (int m = 0; m < 4; ++m)
#pragma unroll
            for (int r = 0; r < 4; ++r) {
                int row = m * 16 + (lane >> 4) * 4 + r;
                stats[row * 16 + w * 2 + 0] = sm[m][r];
                stats[row * 16 + w * 2 + 1] = sq[m][r];
            }
    }
    __syncthreads();
    float mu[4][4], rs[4][4];
#pragma unroll
    for (int m = 0; m < 4; ++m)
#pragma unroll
        for (int r = 0; r < 4; ++r) {
            int row = m * 16 + (lane >> 4) * 4 + r;
            float s = 0.f, s2 = 0.f;
#pragma unroll
            for (int wc = 0; wc < 8; ++wc) {
                s  += stats[row * 16 + wc * 2 + 0];
                s2 += stats[row * 16 + wc * 2 + 1];
            }
            float m_ = s / C1D;
            mu[m][r] = m_;
            rs[m][r] = rsqrtf(s2 / C1D - m_ * m_ + LN_EPS);
        }

    float* Yb = Y + (size_t)b * C1D * LDIM;
#pragma unroll
    for (int ph = 0; ph < 2; ++ph) {
        if ((w >> 2) == ph) {
#pragma unroll
            for (int m = 0; m < 4; ++m)
#pragma unroll
                for (int n = 0; n < 3; ++n)
#pragma unroll
                    for (int r = 0; r < 4; ++r) {
                        int cl = (w & 3) * 48 + n * 16 + (lane & 15);
                        int ll = m * 16 + (lane >> 4) * 4 + r;
                        float v = (acc[m][n][r] + bt[n] - mu[m][r]) * rs[m][r] * gm[n] + bta[n];
                        T[cl * 68 + ll] = v;
                    }
        }
        __syncthreads();
        for (int idx = t; idx < 192 * 64; idx += 512) {
            int cl = idx >> 6, ll = idx & 63;
            Yb[(size_t)(ph * 192 + cl) * LDIM + l0 + ll] = T[cl * 68 + ll];
        }
        __syncthreads();
    }
}

extern "C" void kernel_launch(void* const* d_in, const int* in_sizes, int n_in,
                              void* d_out, int out_size, void* d_ws, size_t ws_size,
                              hipStream_t stream) {
    const float* x1    = (const float*)d_in[0];
    const float* x2    = (const float*)d_in[1];
    const float* Wq    = (const float*)d_in[2];
    const float* bq    = (const float*)d_in[3];
    const float* Wk    = (const float*)d_in[4];
    const float* bk    = (const float*)d_in[5];
    const float* Wv    = (const float*)d_in[6];
    const float* bv    = (const float*)d_in[7];
    const float* Wo    = (const float*)d_in[8];
    const float* bo    = (const float*)d_in[9];
    const float* gamma = (const float*)d_in[10];
    const float* beta  = (const float*)d_in[11];
    float* out = (float*)d_out;

    char* p = (char*)d_ws;
    const size_t NB  = (size_t)BB * LDIM * ADIM;
    unsigned short* X2p = (unsigned short*)p; p += NB;       // B*192*4096 bf16
    unsigned short* KVt = (unsigned short*)p; p += (size_t)BB * 768 * LDIM * 2;  // K rows 0-383, V rows 384-767
    unsigned short* Wkvp= (unsigned short*)p; p += (size_t)768 * C2D * 2;        // Wk pack then Wv pack (adjacent)
    unsigned short* WoTp= (unsigned short*)p; p += (size_t)C1D * ADIM * 2;
    float* bkv    = (float*)p; p += 768 * 4;
    float* kvpart = (float*)p; p += (size_t)BB * NH * KVLC * KVP_STRIDE * 4;
    float* KVf    = (float*)p; p += (size_t)BB * NH * DHD * DHD * 4;
    unsigned short* Mbuf = (unsigned short*)p; p += (size_t)BB * C1D * ADIM * 2;
    unsigned short* WresT = (unsigned short*)p; p += (size_t)BB * C1D * C1D * 2;
    float* btot   = (float*)p; p += (size_t)BB * C1D * 4;

    float inv_scale = powf((float)DHD, -0.25f);

    transpose_cvt<<<dim3(LDIM / 32, C2D / 32, BB), 256, 0, stream>>>(x2, X2p, C2D, LDIM);
    transpose_cvt<<<dim3(ADIM / 32, C2D / 32, 1), 256, 0, stream>>>(Wk, Wkvp, C2D, ADIM);
    transpose_cvt<<<dim3(ADIM / 32, C2D / 32, 1), 256, 0, stream>>>(Wv, Wkvp + (size_t)ADIM * C2D, C2D, ADIM);
    transpose_cvt<<<dim3(C1D / 32, ADIM / 32, 1), 256, 0, stream>>>(Wo, WoTp, ADIM, C1D);
    hipMemcpyAsync(bkv,       bk, ADIM * sizeof(float), hipMemcpyDeviceToDevice, stream);
    hipMemcpyAsync(bkv + ADIM, bv, ADIM * sizeof(float), hipMemcpyDeviceToDevice, stream);

    // KVt[b, 0:384, l] = K (scaled), KVt[b, 384:768, l] = V
    gemm_mfma<C2D, 2><<<dim3(768 / 128, LDIM / 128, BB), 256, 0, stream>>>(
        Wkvp, 0, X2p, (size_t)LDIM * C2D, bkv, KVt, (size_t)768 * LDIM, LDIM,
        inv_scale, 1.0f, ADIM);

    kv_part<<<dim3(KVLC, NH, BB), 64, 0, stream>>>(KVt, kvpart);
    kv_finalize<<<BB * NH, 256, 0, stream>>>(kvpart, KVf);

    m_kernel<<<dim3(C1D / 64, NH, BB), 256, 0, stream>>>(Wq, KVf, Mbuf, inv_scale);
    // W_resT[b][c'][c] = sum_a WoT[c'][a] * M[b][c][a] + (c'==c)   (MFMA)
    gemm_mfma<ADIM, 3><<<dim3(C1D / 128, C1D / 128, BB), 256, 0, stream>>>(
        WoTp, 0, Mbuf, (size_t)C1D * ADIM, bo /*unused*/, WresT, (size_t)C1D * C1D, C1D,
        1.0f, 1.0f, 1 << 30);
    btot_kernel<<<dim3(C1D / 32, BB), 256, 0, stream>>>(bq, KVf, Wo, bo, btot, inv_scale);

    // fused final GEMM (x1 transposed+cvt inline, issue-early) + residual-bias + LN + transposed store
    gemm_ln<<<dim3(LDIM / 64, 1, BB), 512, 0, stream>>>(x1, WresT, btot, gamma, beta, out);
}